// Round 1
// baseline (2385.432 us; speedup 1.0000x reference)
//
#include <hip/hip_runtime.h>
#include <hip/hip_bf16.h>
#include <cfloat>

// ---------- helpers ----------
__device__ __forceinline__ float lrelu(float x, float a) { return x > 0.0f ? x : a * x; }

// monotonic float -> uint encoding for atomicMax on floats
__device__ __forceinline__ unsigned encf(float f) {
    unsigned u = __float_as_uint(f);
    return (u & 0x80000000u) ? ~u : (u | 0x80000000u);
}
__device__ __forceinline__ float decf(unsigned u) {
    unsigned b = (u & 0x80000000u) ? (u ^ 0x80000000u) : ~u;
    return __uint_as_float(b);
}

#define BN_RSQ 0.99999500003749968750f  // 1/sqrt(1+1e-5)

// ---------- init ----------
__global__ void init_mxu(unsigned* __restrict__ p, int n) {
    int t = blockIdx.x * blockDim.x + threadIdx.x;
    if (t < n) p[t] = 0x00800000u;  // encf(-FLT_MAX)
}

// ---------- big GEMM: P = features @ [Wl | Wr]  ([M,1024] x [1024,256]) ----------
__global__ __launch_bounds__(256) void gemm_sage(
    const float* __restrict__ A, const float* __restrict__ Wl, const float* __restrict__ Wr,
    float* __restrict__ P, int M)
{
    __shared__ float As[16][64];
    __shared__ float Bs[16][64];
    const int tid = threadIdx.x;
    const int m0 = blockIdx.y * 64;
    const int j0 = blockIdx.x * 64;             // 0,64,128,192
    const float* B = (j0 < 128) ? Wl : Wr;
    const int jb = j0 & 127;

    const int ty = tid / 16, tx = tid % 16;
    const int la_r = tid / 4, la_c = (tid % 4) * 4;   // A tile: 64 rows x 16 k
    const int lb_k = tid / 16, lb_j = (tid % 16) * 4; // B tile: 16 k x 64 j

    float acc[4][4] = {};
    for (int k0 = 0; k0 < 1024; k0 += 16) {
        float4 av = make_float4(0.f, 0.f, 0.f, 0.f);
        int ar = m0 + la_r;
        if (ar < M) av = *reinterpret_cast<const float4*>(&A[(size_t)ar * 1024 + k0 + la_c]);
        As[la_c + 0][la_r] = av.x;
        As[la_c + 1][la_r] = av.y;
        As[la_c + 2][la_r] = av.z;
        As[la_c + 3][la_r] = av.w;
        float4 bv = *reinterpret_cast<const float4*>(&B[(size_t)(k0 + lb_k) * 128 + jb + lb_j]);
        *reinterpret_cast<float4*>(&Bs[lb_k][lb_j]) = bv;
        __syncthreads();
#pragma unroll
        for (int kk = 0; kk < 16; ++kk) {
            float4 a = *reinterpret_cast<const float4*>(&As[kk][ty * 4]);
            float4 b = *reinterpret_cast<const float4*>(&Bs[kk][tx * 4]);
            float aa[4] = {a.x, a.y, a.z, a.w};
            float bb[4] = {b.x, b.y, b.z, b.w};
#pragma unroll
            for (int i = 0; i < 4; ++i)
#pragma unroll
                for (int j = 0; j < 4; ++j) acc[i][j] += aa[i] * bb[j];
        }
        __syncthreads();
    }
#pragma unroll
    for (int i = 0; i < 4; ++i) {
        int row = m0 + ty * 4 + i;
        if (row < M) {
            float4 st = make_float4(acc[i][0], acc[i][1], acc[i][2], acc[i][3]);
            *reinterpret_cast<float4*>(&P[(size_t)row * 256 + j0 + tx * 4]) = st;
        }
    }
}

// ---------- degrees + edge attr sums + extended edge attr ----------
__global__ void edge_prep(const int* __restrict__ e1d, const int* __restrict__ e2d,
                          const float* __restrict__ ef,
                          float* __restrict__ deg1, float* __restrict__ deg2,
                          float* __restrict__ easum, float* __restrict__ eaext, int E)
{
    int e = blockIdx.x * blockDim.x + threadIdx.x;
    if (e >= E) return;
    atomicAdd(&deg1[e1d[e]], 1.0f);
    int d2 = e2d[e];
    atomicAdd(&deg2[d2], 1.0f);
    float a = ef[e];
    atomicAdd(&easum[d2], a);
    eaext[e] = a;
}

__global__ void self_attr(const float* __restrict__ easum, const float* __restrict__ deg2,
                          float* __restrict__ ea_loop, int N)
{
    int i = blockIdx.x * blockDim.x + threadIdx.x;
    if (i < N) ea_loop[i] = easum[i] / fmaxf(deg2[i], 1.0f);
}

// ---------- SAGE aggregation in projected (128-d) space ----------
__global__ void sage_agg(const int* __restrict__ e1s, const int* __restrict__ e1d,
                         const float* __restrict__ P, float* __restrict__ agg, int E)
{
    int t = blockIdx.x * blockDim.x + threadIdx.x;
    if (t >= E * 32) return;
    int e = t >> 5, g = t & 31;
    int s = e1s[e], d = e1d[e];
    float4 v = *reinterpret_cast<const float4*>(&P[(size_t)s * 256 + g * 4]);
    float* dst = &agg[(size_t)d * 128 + g * 4];
    atomicAdd(dst + 0, v.x);
    atomicAdd(dst + 1, v.y);
    atomicAdd(dst + 2, v.z);
    atomicAdd(dst + 3, v.w);
}

__global__ void x_finish(const float* __restrict__ agg, const float* __restrict__ deg1,
                         const float* __restrict__ P, const float* __restrict__ bl,
                         const float* __restrict__ bng, const float* __restrict__ bnb,
                         float* __restrict__ z, int N)
{
    int t = blockIdx.x * blockDim.x + threadIdx.x;
    if (t >= N * 128) return;
    int n = t >> 7, c = t & 127;
    float x = agg[t] / fmaxf(deg1[n], 1.0f) + bl[c] + P[(size_t)n * 256 + 128 + c];
    x = x * (bng[c] * BN_RSQ) + bnb[c];
    z[(size_t)n * 168 + c] = lrelu(x, 0.01f);
}

// ---------- GATv2 ----------
template <int IND, int HC>
__global__ void gat_lin(const float* __restrict__ X,
                        const float* __restrict__ Wl, const float* __restrict__ bl,
                        const float* __restrict__ Wr, const float* __restrict__ br,
                        float* __restrict__ xl, float* __restrict__ xr, int N)
{
    int t = blockIdx.x * blockDim.x + threadIdx.x;
    if (t >= N * HC) return;
    int n = t / HC, j = t % HC;
    float al = bl[j], ar = br[j];
    const float* xrow = X + (size_t)n * IND;
#pragma unroll 4
    for (int k = 0; k < IND; ++k) {
        float xv = xrow[k];
        al += xv * Wl[k * HC + j];
        ar += xv * Wr[k * HC + j];
    }
    xl[t] = al;
    xr[t] = ar;
}

template <int H, int C>
__global__ void gat_logits(const int* __restrict__ e2s, const int* __restrict__ e2d,
                           const float* __restrict__ eaext,
                           const float* __restrict__ xl, const float* __restrict__ xr,
                           const float* __restrict__ We, const float* __restrict__ att,
                           float* __restrict__ elog, unsigned* __restrict__ mxu, int E, int Eext)
{
    int e = blockIdx.x * blockDim.x + threadIdx.x;
    if (e >= Eext) return;
    int s, d;
    if (e < E) { s = e2s[e]; d = e2d[e]; } else { s = d = e - E; }
    float ea = eaext[e];
    const float* xls = xl + (size_t)s * (H * C);
    const float* xrd = xr + (size_t)d * (H * C);
#pragma unroll
    for (int h = 0; h < H; ++h) {
        float acc = 0.0f;
#pragma unroll
        for (int c = 0; c < C; ++c) {
            float m = xls[h * C + c] + xrd[h * C + c] + ea * We[h * C + c];
            m = lrelu(m, 0.2f);
            acc += m * att[h * C + c];
        }
        elog[(size_t)e * H + h] = acc;
        atomicMax(&mxu[d * H + h], encf(acc));
    }
}

template <int H>
__global__ void gat_expden(const int* __restrict__ e2d, float* __restrict__ elog,
                           const unsigned* __restrict__ mxu, float* __restrict__ den,
                           int E, int Eext)
{
    int t = blockIdx.x * blockDim.x + threadIdx.x;
    if (t >= Eext * H) return;
    int e = t / H, h = t % H;
    int d = (e < E) ? e2d[e] : (e - E);
    float ex = __expf(elog[t] - decf(mxu[d * H + h]));
    elog[t] = ex;
    atomicAdd(&den[d * H + h], ex);
}

template <int H, int C>
__global__ void gat_scatter(const int* __restrict__ e2s, const int* __restrict__ e2d,
                            const float* __restrict__ elog, const float* __restrict__ den,
                            const float* __restrict__ xl, float* __restrict__ gout,
                            int E, int Eext)
{
    int t = blockIdx.x * blockDim.x + threadIdx.x;
    if (t >= Eext * H) return;
    int e = t / H, h = t % H;
    int s, d;
    if (e < E) { s = e2s[e]; d = e2d[e]; } else { s = d = e - E; }
    float alpha = elog[t] / (den[d * H + h] + 1e-16f);
    const float* xls = xl + (size_t)s * (H * C) + h * C;
    float* go = gout + (size_t)d * (H * C) + h * C;
#pragma unroll
    for (int c = 0; c < C; ++c) atomicAdd(&go[c], xls[c] * alpha);
}

__global__ void gat_fin1(const float* __restrict__ gout, const float* __restrict__ b,
                         float* __restrict__ y1, int N)
{
    int t = blockIdx.x * blockDim.x + threadIdx.x;
    if (t >= N * 40) return;
    int j = t % 40;
    y1[t] = lrelu(gout[t] + b[j], 0.01f);
}

__global__ void gat_fin2(const float* __restrict__ gout, const float* __restrict__ b,
                         const float* __restrict__ bng, const float* __restrict__ bnb,
                         float* __restrict__ z, int N)
{
    int t = blockIdx.x * blockDim.x + threadIdx.x;
    if (t >= N * 20) return;
    int n = t / 20, j = t % 20;
    float v = gout[t] + b[j];
    v = v * (bng[j] * BN_RSQ) + bnb[j];
    z[(size_t)n * 168 + 128 + j] = lrelu(v, 0.01f);
}

__global__ void copy_addf(const float* __restrict__ addf, float* __restrict__ z, int N)
{
    int t = blockIdx.x * blockDim.x + threadIdx.x;
    if (t >= N * 20) return;
    int n = t / 20, j = t % 20;
    z[(size_t)n * 168 + 148 + j] = addf[t];
}

// ---------- MLP head ----------
__global__ __launch_bounds__(256) void mlp_head(
    const float* __restrict__ z, const float* __restrict__ fc1W, const float* __restrict__ fc1b,
    const float* __restrict__ bnfg, const float* __restrict__ bnfb,
    const float* __restrict__ fc2W, const float* __restrict__ fc2b,
    float* __restrict__ out, int N)
{
    __shared__ float zs[32][169];
    __shared__ float ts[32][169];
    const int n0 = blockIdx.x * 32;
    const int tid = threadIdx.x;
    for (int idx = tid; idx < 32 * 168; idx += 256) {
        int ln = idx / 168, k = idx % 168;
        int n = n0 + ln;
        zs[ln][k] = (n < N) ? z[(size_t)n * 168 + k] : 0.0f;
    }
    __syncthreads();
    const int ln = tid / 8, jl = tid % 8;
    for (int j = jl; j < 168; j += 8) {
        float acc = fc1b[j];
#pragma unroll 4
        for (int k = 0; k < 168; ++k) acc += zs[ln][k] * fc1W[k * 168 + j];
        acc = acc * (bnfg[j] * BN_RSQ) + bnfb[j];
        ts[ln][j] = fmaxf(acc, 0.0f);
    }
    __syncthreads();
    if (jl < 3) {
        float acc = fc2b[jl];
#pragma unroll 4
        for (int k = 0; k < 168; ++k) acc += ts[ln][k] * fc2W[k * 3 + jl];
        int n = n0 + ln;
        if (n < N) out[(size_t)n * 3 + jl] = acc;
    }
}

// ---------- launch ----------
extern "C" void kernel_launch(void* const* d_in, const int* in_sizes, int n_in,
                              void* d_out, int out_size, void* d_ws, size_t ws_size,
                              hipStream_t stream)
{
    const float* features = (const float*)d_in[0];
    const int*   e1       = (const int*)d_in[1];
    const int*   e2       = (const int*)d_in[2];
    const float* ef       = (const float*)d_in[3];
    const float* addf     = (const float*)d_in[4];
    const float* sage_Wl  = (const float*)d_in[5];
    const float* sage_bl  = (const float*)d_in[6];
    const float* sage_Wr  = (const float*)d_in[7];
    const float* g1_Wl = (const float*)d_in[8];
    const float* g1_bl = (const float*)d_in[9];
    const float* g1_Wr = (const float*)d_in[10];
    const float* g1_br = (const float*)d_in[11];
    const float* g1_We = (const float*)d_in[12];
    const float* g1_att = (const float*)d_in[13];
    const float* g1_b = (const float*)d_in[14];
    const float* g2_Wl = (const float*)d_in[15];
    const float* g2_bl = (const float*)d_in[16];
    const float* g2_Wr = (const float*)d_in[17];
    const float* g2_br = (const float*)d_in[18];
    const float* g2_We = (const float*)d_in[19];
    const float* g2_att = (const float*)d_in[20];
    const float* g2_b = (const float*)d_in[21];
    const float* fc1_W = (const float*)d_in[22];
    const float* fc1_b = (const float*)d_in[23];
    const float* fc2_W = (const float*)d_in[24];
    const float* fc2_b = (const float*)d_in[25];
    const float* bnx_g = (const float*)d_in[26];
    const float* bnx_b = (const float*)d_in[27];
    const float* bny_g = (const float*)d_in[28];
    const float* bny_b = (const float*)d_in[29];
    const float* bnf_g = (const float*)d_in[30];
    const float* bnf_b = (const float*)d_in[31];

    const int N = in_sizes[0] / 1024;
    const int E = in_sizes[3];
    const int Eext = E + N;
    const int* e1s = e1, *e1d = e1 + E;
    const int* e2s = e2, *e2d = e2 + E;

    float* w = (float*)d_ws;
    size_t off = 0;
    auto take = [&](size_t n) { float* p = w + off; off += (n + 3) & ~(size_t)3; return p; };
    float* P     = take((size_t)N * 256);
    float* agg   = take((size_t)N * 128);
    float* deg1  = take(N);
    float* deg2  = take(N);
    float* easum = take(N);
    float* eaext = take(Eext);
    float* xl1   = take((size_t)N * 40);
    float* xr1   = take((size_t)N * 40);
    float* elog1 = take((size_t)Eext * 4);
    unsigned* mxu1 = (unsigned*)take((size_t)N * 4);
    float* den1  = take((size_t)N * 4);
    float* gout1 = take((size_t)N * 40);
    float* y1    = take((size_t)N * 40);
    float* xl2   = take((size_t)N * 20);
    float* xr2   = take((size_t)N * 20);
    float* elog2 = take((size_t)Eext * 4);
    unsigned* mxu2 = (unsigned*)take((size_t)N * 4);
    float* den2  = take((size_t)N * 4);
    float* gout2 = take((size_t)N * 20);
    float* z     = take((size_t)N * 168);

    hipMemsetAsync(agg,   0, (size_t)N * 128 * 4, stream);
    hipMemsetAsync(deg1,  0, (size_t)N * 4, stream);
    hipMemsetAsync(deg2,  0, (size_t)N * 4, stream);
    hipMemsetAsync(easum, 0, (size_t)N * 4, stream);
    hipMemsetAsync(den1,  0, (size_t)N * 16, stream);
    hipMemsetAsync(den2,  0, (size_t)N * 16, stream);
    hipMemsetAsync(gout1, 0, (size_t)N * 160, stream);
    hipMemsetAsync(gout2, 0, (size_t)N * 80, stream);

    const int B = 256;
    init_mxu<<<(N * 4 + B - 1) / B, B, 0, stream>>>(mxu1, N * 4);
    init_mxu<<<(N * 4 + B - 1) / B, B, 0, stream>>>(mxu2, N * 4);

    gemm_sage<<<dim3(4, (N + 63) / 64), 256, 0, stream>>>(features, sage_Wl, sage_Wr, P, N);

    edge_prep<<<(E + B - 1) / B, B, 0, stream>>>(e1d, e2d, ef, deg1, deg2, easum, eaext, E);
    self_attr<<<(N + B - 1) / B, B, 0, stream>>>(easum, deg2, eaext + E, N);

    sage_agg<<<(E * 32 + B - 1) / B, B, 0, stream>>>(e1s, e1d, P, agg, E);
    x_finish<<<(N * 128 + B - 1) / B, B, 0, stream>>>(agg, deg1, P, sage_bl, bnx_g, bnx_b, z, N);

    // GAT layer 1 (20 -> 4x10)
    gat_lin<20, 40><<<(N * 40 + B - 1) / B, B, 0, stream>>>(addf, g1_Wl, g1_bl, g1_Wr, g1_br, xl1, xr1, N);
    gat_logits<4, 10><<<(Eext + B - 1) / B, B, 0, stream>>>(e2s, e2d, eaext, xl1, xr1, g1_We, g1_att, elog1, mxu1, E, Eext);
    gat_expden<4><<<(Eext * 4 + B - 1) / B, B, 0, stream>>>(e2d, elog1, mxu1, den1, E, Eext);
    gat_scatter<4, 10><<<(Eext * 4 + B - 1) / B, B, 0, stream>>>(e2s, e2d, elog1, den1, xl1, gout1, E, Eext);
    gat_fin1<<<(N * 40 + B - 1) / B, B, 0, stream>>>(gout1, g1_b, y1, N);

    // GAT layer 2 (40 -> 4x5)
    gat_lin<40, 20><<<(N * 20 + B - 1) / B, B, 0, stream>>>(y1, g2_Wl, g2_bl, g2_Wr, g2_br, xl2, xr2, N);
    gat_logits<4, 5><<<(Eext + B - 1) / B, B, 0, stream>>>(e2s, e2d, eaext, xl2, xr2, g2_We, g2_att, elog2, mxu2, E, Eext);
    gat_expden<4><<<(Eext * 4 + B - 1) / B, B, 0, stream>>>(e2d, elog2, mxu2, den2, E, Eext);
    gat_scatter<4, 5><<<(Eext * 4 + B - 1) / B, B, 0, stream>>>(e2s, e2d, elog2, den2, xl2, gout2, E, Eext);
    gat_fin2<<<(N * 20 + B - 1) / B, B, 0, stream>>>(gout2, g2_b, bny_g, bny_b, z, N);

    copy_addf<<<(N * 20 + B - 1) / B, B, 0, stream>>>(addf, z, N);

    mlp_head<<<(N + 31) / 32, 256, 0, stream>>>(z, fc1_W, fc1_b, bnf_g, bnf_b, fc2_W, fc2_b, (float*)d_out, N);
}

// Round 2
// 1143.305 us; speedup vs baseline: 2.0864x; 2.0864x over previous
//
#include <hip/hip_runtime.h>
#include <hip/hip_bf16.h>
#include <cfloat>

__device__ __forceinline__ float lrelu(float x, float a) { return x > 0.0f ? x : a * x; }

#define BN_RSQ 0.99999500003749968750f  // 1/sqrt(1+1e-5)
#define SCAN_B 256

// ---------- big GEMM: P = features @ [Wl | Wr]  ([M,1024] x [1024,256]) ----------
__global__ __launch_bounds__(256) void gemm_sage(
    const float* __restrict__ A, const float* __restrict__ Wl, const float* __restrict__ Wr,
    float* __restrict__ P, int M)
{
    __shared__ float As[16][64];
    __shared__ float Bs[16][64];
    const int tid = threadIdx.x;
    const int m0 = blockIdx.y * 64;
    const int j0 = blockIdx.x * 64;             // 0,64,128,192
    const float* B = (j0 < 128) ? Wl : Wr;
    const int jb = j0 & 127;

    const int ty = tid / 16, tx = tid % 16;
    const int la_r = tid / 4, la_c = (tid % 4) * 4;   // A tile: 64 rows x 16 k
    const int lb_k = tid / 16, lb_j = (tid % 16) * 4; // B tile: 16 k x 64 j

    float acc[4][4] = {};
    for (int k0 = 0; k0 < 1024; k0 += 16) {
        float4 av = make_float4(0.f, 0.f, 0.f, 0.f);
        int ar = m0 + la_r;
        if (ar < M) av = *reinterpret_cast<const float4*>(&A[(size_t)ar * 1024 + k0 + la_c]);
        As[la_c + 0][la_r] = av.x;
        As[la_c + 1][la_r] = av.y;
        As[la_c + 2][la_r] = av.z;
        As[la_c + 3][la_r] = av.w;
        float4 bv = *reinterpret_cast<const float4*>(&B[(size_t)(k0 + lb_k) * 128 + jb + lb_j]);
        *reinterpret_cast<float4*>(&Bs[lb_k][lb_j]) = bv;
        __syncthreads();
#pragma unroll
        for (int kk = 0; kk < 16; ++kk) {
            float4 a = *reinterpret_cast<const float4*>(&As[kk][ty * 4]);
            float4 b = *reinterpret_cast<const float4*>(&Bs[kk][tx * 4]);
            float aa[4] = {a.x, a.y, a.z, a.w};
            float bb[4] = {b.x, b.y, b.z, b.w};
#pragma unroll
            for (int i = 0; i < 4; ++i)
#pragma unroll
                for (int j = 0; j < 4; ++j) acc[i][j] += aa[i] * bb[j];
        }
        __syncthreads();
    }
#pragma unroll
    for (int i = 0; i < 4; ++i) {
        int row = m0 + ty * 4 + i;
        if (row < M) {
            float4 st = make_float4(acc[i][0], acc[i][1], acc[i][2], acc[i][3]);
            *reinterpret_cast<float4*>(&P[(size_t)row * 256 + j0 + tx * 4]) = st;
        }
    }
}

// ---------- degree histograms + edge-attr sums ----------
__global__ void edge_count(const int* __restrict__ e1d, const int* __restrict__ e2d,
                           const float* __restrict__ ef,
                           int* __restrict__ cnt1, int* __restrict__ cnt2,
                           float* __restrict__ easum, float* __restrict__ eaext, int E)
{
    int e = blockIdx.x * blockDim.x + threadIdx.x;
    if (e >= E) return;
    atomicAdd(&cnt1[e1d[e]], 1);
    int d2 = e2d[e];
    atomicAdd(&cnt2[d2], 1);
    float a = ef[e];
    atomicAdd(&easum[d2], a);
    eaext[e] = a;
}

__global__ void self_attr(const float* __restrict__ easum, const int* __restrict__ cnt2,
                          float* __restrict__ ea_loop, int N)
{
    int i = blockIdx.x * blockDim.x + threadIdx.x;
    if (i < N) ea_loop[i] = easum[i] / fmaxf((float)cnt2[i], 1.0f);
}

// ---------- exclusive scan (M <= 65536) ----------
__global__ void scan1(const int* __restrict__ cnt, int add1, int* __restrict__ excl,
                      int* __restrict__ bsum, int M)
{
    __shared__ int sh[SCAN_B];
    int i = blockIdx.x * SCAN_B + threadIdx.x;
    int v = (i < M) ? cnt[i] + add1 : 0;
    sh[threadIdx.x] = v;
    __syncthreads();
    for (int o = 1; o < SCAN_B; o <<= 1) {
        int t = (threadIdx.x >= o) ? sh[threadIdx.x - o] : 0;
        __syncthreads();
        sh[threadIdx.x] += t;
        __syncthreads();
    }
    if (i < M) excl[i] = sh[threadIdx.x] - v;
    if (threadIdx.x == SCAN_B - 1) bsum[blockIdx.x] = sh[threadIdx.x];
}

__global__ void scan2(int* __restrict__ bsum, int nb)
{
    __shared__ int sh[SCAN_B];
    int v = (threadIdx.x < nb) ? bsum[threadIdx.x] : 0;
    sh[threadIdx.x] = v;
    __syncthreads();
    for (int o = 1; o < SCAN_B; o <<= 1) {
        int t = (threadIdx.x >= o) ? sh[threadIdx.x - o] : 0;
        __syncthreads();
        sh[threadIdx.x] += t;
        __syncthreads();
    }
    if (threadIdx.x < nb) bsum[threadIdx.x] = sh[threadIdx.x] - v;  // exclusive
}

__global__ void scan3(int* __restrict__ excl, const int* __restrict__ bsum, int M)
{
    int i = blockIdx.x * SCAN_B + threadIdx.x;
    if (i < M) excl[i] += bsum[blockIdx.x];
}

// ---------- CSR fill ----------
__global__ void fill1(const int* __restrict__ e1s, const int* __restrict__ e1d,
                      const int* __restrict__ off1, int* __restrict__ cur1,
                      int* __restrict__ srcs1, int E)
{
    int e = blockIdx.x * blockDim.x + threadIdx.x;
    if (e >= E) return;
    int d = e1d[e];
    int pos = atomicAdd(&cur1[d], 1);
    srcs1[off1[d] + pos] = e1s[e];
}

__global__ void fill2(const int* __restrict__ e2d,
                      const int* __restrict__ off2, int* __restrict__ cur2,
                      int* __restrict__ eidx2, int E, int Eext)
{
    int t = blockIdx.x * blockDim.x + threadIdx.x;
    if (t >= Eext) return;
    int d = (t < E) ? e2d[t] : (t - E);
    int pos = atomicAdd(&cur2[d], 1);
    eidx2[off2[d] + pos] = t;
}

// ---------- SAGE: gather in projected 128-d space, fused epilogue into z ----------
__global__ void sage_gather(const int* __restrict__ srcs1, const int* __restrict__ off1,
                            const int* __restrict__ cnt1, const float* __restrict__ P,
                            const float* __restrict__ bl,
                            const float* __restrict__ bng, const float* __restrict__ bnb,
                            float* __restrict__ z, int N)
{
    int t = blockIdx.x * blockDim.x + threadIdx.x;
    if (t >= N * 32) return;
    int n = t >> 5, g = t & 31;
    int beg = off1[n], dg = cnt1[n];
    float4 acc = make_float4(0.f, 0.f, 0.f, 0.f);
    for (int j = beg; j < beg + dg; ++j) {
        int s = srcs1[j];
        float4 v = *reinterpret_cast<const float4*>(&P[(size_t)s * 256 + g * 4]);
        acc.x += v.x; acc.y += v.y; acc.z += v.z; acc.w += v.w;
    }
    float inv = 1.0f / fmaxf((float)dg, 1.0f);
    float a4[4] = {acc.x, acc.y, acc.z, acc.w};
#pragma unroll
    for (int k = 0; k < 4; ++k) {
        int c = g * 4 + k;
        float x = a4[k] * inv + bl[c] + P[(size_t)n * 256 + 128 + c];
        x = x * (bng[c] * BN_RSQ) + bnb[c];
        z[(size_t)n * 168 + c] = lrelu(x, 0.01f);
    }
}

// ---------- GATv2 linear projections ----------
template <int IND, int HC>
__global__ void gat_lin(const float* __restrict__ X,
                        const float* __restrict__ Wl, const float* __restrict__ bl,
                        const float* __restrict__ Wr, const float* __restrict__ br,
                        float* __restrict__ xl, float* __restrict__ xr, int N)
{
    int t = blockIdx.x * blockDim.x + threadIdx.x;
    if (t >= N * HC) return;
    int n = t / HC, j = t % HC;
    float al = bl[j], ar = br[j];
    const float* xrow = X + (size_t)n * IND;
#pragma unroll 4
    for (int k = 0; k < IND; ++k) {
        float xv = xrow[k];
        al += xv * Wl[k * HC + j];
        ar += xv * Wr[k * HC + j];
    }
    xl[t] = al;
    xr[t] = ar;
}

// ---------- fused GATv2 per (node, head): logits + segment softmax + weighted sum ----------
// MODE 1: y = lrelu(out + b, 0.01)            -> Y (N x H*C)
// MODE 2: z[.,128..148) = lrelu(bn(out + b))  -> Z rows (stride 168)
template <int H, int C, int MODE>
__global__ void gat_node(const int* __restrict__ eidx2, const int* __restrict__ off2,
                         const int* __restrict__ cnt2, const int* __restrict__ e2s,
                         const float* __restrict__ eaext,
                         const float* __restrict__ xl, const float* __restrict__ xr,
                         const float* __restrict__ We, const float* __restrict__ att,
                         const float* __restrict__ b,
                         const float* __restrict__ bng, const float* __restrict__ bnb,
                         float* __restrict__ slog, float* __restrict__ out,
                         int E, int N)
{
    int t = blockIdx.x * blockDim.x + threadIdx.x;
    if (t >= N * H) return;
    int n = t / H, h = t % H;

    float xrc[C], atth[C], weh[C];
#pragma unroll
    for (int c = 0; c < C; ++c) {
        xrc[c]  = xr[(size_t)n * (H * C) + h * C + c];
        atth[c] = att[h * C + c];
        weh[c]  = We[h * C + c];
    }

    const int beg = off2[n];
    const int dg = cnt2[n] + 1;  // + self loop

    float mx = -FLT_MAX;
    for (int jj = 0; jj < dg; ++jj) {
        int j = beg + jj;
        int e = eidx2[j];
        int s = (e < E) ? e2s[e] : (e - E);
        float ea = eaext[e];
        const float* xls = xl + (size_t)s * (H * C) + h * C;
        float acc = 0.0f;
#pragma unroll
        for (int c = 0; c < C; ++c) {
            float m = xls[c] + xrc[c] + ea * weh[c];
            acc += lrelu(m, 0.2f) * atth[c];
        }
        slog[(size_t)j * H + h] = acc;
        mx = fmaxf(mx, acc);
    }

    float den = 0.0f;
    float accv[C] = {};
    for (int jj = 0; jj < dg; ++jj) {
        int j = beg + jj;
        int e = eidx2[j];
        int s = (e < E) ? e2s[e] : (e - E);
        float ex = __expf(slog[(size_t)j * H + h] - mx);
        den += ex;
        const float* xls = xl + (size_t)s * (H * C) + h * C;
#pragma unroll
        for (int c = 0; c < C; ++c) accv[c] += ex * xls[c];
    }
    float inv = 1.0f / (den + 1e-16f);

#pragma unroll
    for (int c = 0; c < C; ++c) {
        int jch = h * C + c;
        float v = accv[c] * inv + b[jch];
        if (MODE == 1) {
            out[(size_t)n * (H * C) + jch] = lrelu(v, 0.01f);
        } else {
            v = v * (bng[jch] * BN_RSQ) + bnb[jch];
            out[(size_t)n * 168 + 128 + jch] = lrelu(v, 0.01f);
        }
    }
}

__global__ void copy_addf(const float* __restrict__ addf, float* __restrict__ z, int N)
{
    int t = blockIdx.x * blockDim.x + threadIdx.x;
    if (t >= N * 20) return;
    int n = t / 20, j = t % 20;
    z[(size_t)n * 168 + 148 + j] = addf[t];
}

// ---------- MLP head ----------
__global__ __launch_bounds__(256) void mlp_head(
    const float* __restrict__ z, const float* __restrict__ fc1W, const float* __restrict__ fc1b,
    const float* __restrict__ bnfg, const float* __restrict__ bnfb,
    const float* __restrict__ fc2W, const float* __restrict__ fc2b,
    float* __restrict__ out, int N)
{
    __shared__ float zs[32][169];
    __shared__ float ts[32][169];
    const int n0 = blockIdx.x * 32;
    const int tid = threadIdx.x;
    for (int idx = tid; idx < 32 * 168; idx += 256) {
        int ln = idx / 168, k = idx % 168;
        int n = n0 + ln;
        zs[ln][k] = (n < N) ? z[(size_t)n * 168 + k] : 0.0f;
    }
    __syncthreads();
    const int ln = tid / 8, jl = tid % 8;
    for (int j = jl; j < 168; j += 8) {
        float acc = fc1b[j];
#pragma unroll 4
        for (int k = 0; k < 168; ++k) acc += zs[ln][k] * fc1W[k * 168 + j];
        acc = acc * (bnfg[j] * BN_RSQ) + bnfb[j];
        ts[ln][j] = fmaxf(acc, 0.0f);
    }
    __syncthreads();
    if (jl < 3) {
        float acc = fc2b[jl];
#pragma unroll 4
        for (int k = 0; k < 168; ++k) acc += ts[ln][k] * fc2W[k * 3 + jl];
        int n = n0 + ln;
        if (n < N) out[(size_t)n * 3 + jl] = acc;
    }
}

// ---------- launch ----------
extern "C" void kernel_launch(void* const* d_in, const int* in_sizes, int n_in,
                              void* d_out, int out_size, void* d_ws, size_t ws_size,
                              hipStream_t stream)
{
    const float* features = (const float*)d_in[0];
    const int*   e1       = (const int*)d_in[1];
    const int*   e2       = (const int*)d_in[2];
    const float* ef       = (const float*)d_in[3];
    const float* addf     = (const float*)d_in[4];
    const float* sage_Wl  = (const float*)d_in[5];
    const float* sage_bl  = (const float*)d_in[6];
    const float* sage_Wr  = (const float*)d_in[7];
    const float* g1_Wl = (const float*)d_in[8];
    const float* g1_bl = (const float*)d_in[9];
    const float* g1_Wr = (const float*)d_in[10];
    const float* g1_br = (const float*)d_in[11];
    const float* g1_We = (const float*)d_in[12];
    const float* g1_att = (const float*)d_in[13];
    const float* g1_b = (const float*)d_in[14];
    const float* g2_Wl = (const float*)d_in[15];
    const float* g2_bl = (const float*)d_in[16];
    const float* g2_Wr = (const float*)d_in[17];
    const float* g2_br = (const float*)d_in[18];
    const float* g2_We = (const float*)d_in[19];
    const float* g2_att = (const float*)d_in[20];
    const float* g2_b = (const float*)d_in[21];
    const float* fc1_W = (const float*)d_in[22];
    const float* fc1_b = (const float*)d_in[23];
    const float* fc2_W = (const float*)d_in[24];
    const float* fc2_b = (const float*)d_in[25];
    const float* bnx_g = (const float*)d_in[26];
    const float* bnx_b = (const float*)d_in[27];
    const float* bny_g = (const float*)d_in[28];
    const float* bny_b = (const float*)d_in[29];
    const float* bnf_g = (const float*)d_in[30];
    const float* bnf_b = (const float*)d_in[31];

    const int N = in_sizes[0] / 1024;
    const int E = in_sizes[3];
    const int Eext = E + N;
    const int* e1s = e1, *e1d = e1 + E;
    const int* e2s = e2, *e2d = e2 + E;
    const int nb = (N + SCAN_B - 1) / SCAN_B;

    char* wb = (char*)d_ws;
    size_t off = 0;
    auto takeB = [&](size_t bytes) { char* p = wb + off; off = (off + bytes + 255) & ~(size_t)255; return p; };
    float* P     = (float*)takeB((size_t)N * 256 * 4);
    float* z     = (float*)takeB((size_t)N * 168 * 4);
    float* eaext = (float*)takeB((size_t)Eext * 4);
    float* easum = (float*)takeB((size_t)N * 4);
    float* xl1   = (float*)takeB((size_t)N * 40 * 4);
    float* xr1   = (float*)takeB((size_t)N * 40 * 4);
    float* y1    = (float*)takeB((size_t)N * 40 * 4);
    float* xl2   = (float*)takeB((size_t)N * 20 * 4);
    float* xr2   = (float*)takeB((size_t)N * 20 * 4);
    float* slog  = (float*)takeB((size_t)Eext * 4 * 4);
    int* cnt1  = (int*)takeB((size_t)N * 4);
    int* cnt2  = (int*)takeB((size_t)N * 4);
    int* cur1  = (int*)takeB((size_t)N * 4);
    int* cur2  = (int*)takeB((size_t)N * 4);
    int* off1  = (int*)takeB((size_t)N * 4);
    int* off2  = (int*)takeB((size_t)N * 4);
    int* bsum1 = (int*)takeB(SCAN_B * 4);
    int* bsum2 = (int*)takeB(SCAN_B * 4);
    int* srcs1 = (int*)takeB((size_t)E * 4);
    int* eidx2 = (int*)takeB((size_t)Eext * 4);

    hipMemsetAsync(cnt1, 0, (size_t)N * 4, stream);
    hipMemsetAsync(cnt2, 0, (size_t)N * 4, stream);
    hipMemsetAsync(cur1, 0, (size_t)N * 4, stream);
    hipMemsetAsync(cur2, 0, (size_t)N * 4, stream);
    hipMemsetAsync(easum, 0, (size_t)N * 4, stream);

    const int B = 256;
    // histograms + edge attrs
    edge_count<<<(E + B - 1) / B, B, 0, stream>>>(e1d, e2d, ef, cnt1, cnt2, easum, eaext, E);
    self_attr<<<(N + B - 1) / B, B, 0, stream>>>(easum, cnt2, eaext + E, N);

    // CSR offsets
    scan1<<<nb, SCAN_B, 0, stream>>>(cnt1, 0, off1, bsum1, N);
    scan2<<<1, SCAN_B, 0, stream>>>(bsum1, nb);
    scan3<<<nb, SCAN_B, 0, stream>>>(off1, bsum1, N);
    scan1<<<nb, SCAN_B, 0, stream>>>(cnt2, 1, off2, bsum2, N);
    scan2<<<1, SCAN_B, 0, stream>>>(bsum2, nb);
    scan3<<<nb, SCAN_B, 0, stream>>>(off2, bsum2, N);

    // CSR fill
    fill1<<<(E + B - 1) / B, B, 0, stream>>>(e1s, e1d, off1, cur1, srcs1, E);
    fill2<<<(Eext + B - 1) / B, B, 0, stream>>>(e2d, off2, cur2, eidx2, E, Eext);

    // SAGE
    gemm_sage<<<dim3(4, (N + 63) / 64), 256, 0, stream>>>(features, sage_Wl, sage_Wr, P, N);
    sage_gather<<<(N * 32 + B - 1) / B, B, 0, stream>>>(srcs1, off1, cnt1, P, sage_bl, bnx_g, bnx_b, z, N);

    // GAT layer 1 (20 -> 4x10)
    gat_lin<20, 40><<<(N * 40 + B - 1) / B, B, 0, stream>>>(addf, g1_Wl, g1_bl, g1_Wr, g1_br, xl1, xr1, N);
    gat_node<4, 10, 1><<<(N * 4 + B - 1) / B, B, 0, stream>>>(
        eidx2, off2, cnt2, e2s, eaext, xl1, xr1, g1_We, g1_att, g1_b,
        nullptr, nullptr, slog, y1, E, N);

    // GAT layer 2 (40 -> 4x5)
    gat_lin<40, 20><<<(N * 20 + B - 1) / B, B, 0, stream>>>(y1, g2_Wl, g2_bl, g2_Wr, g2_br, xl2, xr2, N);
    gat_node<4, 5, 2><<<(N * 4 + B - 1) / B, B, 0, stream>>>(
        eidx2, off2, cnt2, e2s, eaext, xl2, xr2, g2_We, g2_att, g2_b,
        bny_g, bny_b, slog, z, E, N);

    copy_addf<<<(N * 20 + B - 1) / B, B, 0, stream>>>(addf, z, N);

    mlp_head<<<(N + 31) / 32, 256, 0, stream>>>(z, fc1_W, fc1_b, bnf_g, bnf_b, fc2_W, fc2_b, (float*)d_out, N);
}

// Round 3
// 502.896 us; speedup vs baseline: 4.7434x; 2.2734x over previous
//
#include <hip/hip_runtime.h>
#include <hip/hip_bf16.h>
#include <cfloat>

__device__ __forceinline__ float lrelu(float x, float a) { return x > 0.0f ? x : a * x; }

// fp32 -> bf16 round-to-nearest-even (bit pattern)
__device__ __forceinline__ unsigned short f2bf(float f) {
    unsigned u = __float_as_uint(f);
    unsigned r = (u + 0x7FFFu + ((u >> 16) & 1u)) >> 16;
    return (unsigned short)r;
}

typedef __attribute__((ext_vector_type(8))) short short8;
typedef __attribute__((ext_vector_type(4))) float f32x4;

#define BN_RSQ 0.99999500003749968750f  // 1/sqrt(1+1e-5)
#define SCAN_B 256

// ---------- weight conversion/transpose ----------
// Bt[256][1024] bf16: Bt[c][k] = (c<128 ? Wl[k][c] : Wr[k][c-128])
__global__ void conv_wsage(const float* __restrict__ Wl, const float* __restrict__ Wr,
                           unsigned short* __restrict__ Bt)
{
    int t = blockIdx.x * blockDim.x + threadIdx.x;
    if (t >= 256 * 1024) return;
    int c = t >> 10, k = t & 1023;
    float v = (c < 128) ? Wl[(size_t)k * 128 + c] : Wr[(size_t)k * 128 + (c - 128)];
    Bt[(size_t)c * 1024 + k] = f2bf(v);
}

// Bt1[192][192] bf16 zero-padded: Bt1[c][k] = fc1W[k][c] for c,k<168
__global__ void conv_wfc1(const float* __restrict__ fc1W, unsigned short* __restrict__ Bt1)
{
    int t = blockIdx.x * blockDim.x + threadIdx.x;
    if (t >= 192 * 192) return;
    int c = t / 192, k = t % 192;
    float v = (c < 168 && k < 168) ? fc1W[(size_t)k * 168 + c] : 0.0f;
    Bt1[(size_t)c * 192 + k] = f2bf(v);
}

// ---------- SAGE GEMM via MFMA: P = features @ [Wl|Wr], [M,1024]x[1024,256] ----------
// block: 64 rows x 256 cols; 4 waves, each 64 rows x 64 cols (4x4 fragments of 16x16).
__global__ __launch_bounds__(256) void gemm_sage_mfma(
    const float* __restrict__ A, const unsigned short* __restrict__ Bt,
    float* __restrict__ P, int M)
{
    const int tid = threadIdx.x;
    const int wid = tid >> 6, lane = tid & 63;
    const int m0 = blockIdx.x * 64;
    const int l16 = lane & 15, g = lane >> 4;
    const int colbase = wid * 64 + l16;

    f32x4 acc[4][4] = {};

    for (int k0 = 0; k0 < 1024; k0 += 32) {
        const int kb = k0 + g * 8;
        short8 afr[4];
#pragma unroll
        for (int fm = 0; fm < 4; ++fm) {
            int row = m0 + fm * 16 + l16;
            float4 v0 = make_float4(0.f, 0.f, 0.f, 0.f);
            float4 v1 = make_float4(0.f, 0.f, 0.f, 0.f);
            if (row < M) {
                const float* p = &A[(size_t)row * 1024 + kb];
                v0 = *reinterpret_cast<const float4*>(p);
                v1 = *reinterpret_cast<const float4*>(p + 4);
            }
            short8 a;
            a[0] = (short)f2bf(v0.x); a[1] = (short)f2bf(v0.y);
            a[2] = (short)f2bf(v0.z); a[3] = (short)f2bf(v0.w);
            a[4] = (short)f2bf(v1.x); a[5] = (short)f2bf(v1.y);
            a[6] = (short)f2bf(v1.z); a[7] = (short)f2bf(v1.w);
            afr[fm] = a;
        }
        short8 bfr[4];
#pragma unroll
        for (int fn = 0; fn < 4; ++fn) {
            int col = colbase + fn * 16;
            bfr[fn] = *reinterpret_cast<const short8*>(&Bt[(size_t)col * 1024 + kb]);
        }
#pragma unroll
        for (int fm = 0; fm < 4; ++fm)
#pragma unroll
            for (int fn = 0; fn < 4; ++fn)
                acc[fm][fn] = __builtin_amdgcn_mfma_f32_16x16x32_bf16(
                    afr[fm], bfr[fn], acc[fm][fn], 0, 0, 0);
    }

#pragma unroll
    for (int fm = 0; fm < 4; ++fm) {
#pragma unroll
        for (int r = 0; r < 4; ++r) {
            int row = m0 + fm * 16 + g * 4 + r;
            if (row < M) {
#pragma unroll
                for (int fn = 0; fn < 4; ++fn)
                    P[(size_t)row * 256 + colbase + fn * 16] = acc[fm][fn][r];
            }
        }
    }
}

// ---------- MLP head via MFMA: t = relu(bn(z@fc1W+b)); out = t@fc2W + b2 ----------
// block: 64 rows; waves 0..2 cover cols 0..191 (fc1, K padded to 192); fc2 from LDS.
__global__ __launch_bounds__(256) void mlp_mfma(
    const float* __restrict__ z, const unsigned short* __restrict__ Bt1,
    const float* __restrict__ fc1b, const float* __restrict__ bnfg, const float* __restrict__ bnfb,
    const float* __restrict__ fc2W, const float* __restrict__ fc2b,
    float* __restrict__ out, int M)
{
    __shared__ float ts[64][169];
    const int tid = threadIdx.x;
    const int wid = tid >> 6, lane = tid & 63;
    const int m0 = blockIdx.x * 64;
    const int l16 = lane & 15, g = lane >> 4;

    if (wid < 3) {
        const int colbase = wid * 64 + l16;
        f32x4 acc[4][4] = {};
        for (int k0 = 0; k0 < 192; k0 += 32) {
            const int kb = k0 + g * 8;
            short8 afr[4];
#pragma unroll
            for (int fm = 0; fm < 4; ++fm) {
                int row = m0 + fm * 16 + l16;
                float4 v0 = make_float4(0.f, 0.f, 0.f, 0.f);
                float4 v1 = make_float4(0.f, 0.f, 0.f, 0.f);
                if (row < M && kb < 168) {
                    const float* p = &z[(size_t)row * 168 + kb];
                    v0 = *reinterpret_cast<const float4*>(p);
                    v1 = *reinterpret_cast<const float4*>(p + 4);
                }
                short8 a;
                a[0] = (short)f2bf(v0.x); a[1] = (short)f2bf(v0.y);
                a[2] = (short)f2bf(v0.z); a[3] = (short)f2bf(v0.w);
                a[4] = (short)f2bf(v1.x); a[5] = (short)f2bf(v1.y);
                a[6] = (short)f2bf(v1.z); a[7] = (short)f2bf(v1.w);
                afr[fm] = a;
            }
            short8 bfr[4];
#pragma unroll
            for (int fn = 0; fn < 4; ++fn) {
                int col = colbase + fn * 16;
                bfr[fn] = *reinterpret_cast<const short8*>(&Bt1[(size_t)col * 192 + kb]);
            }
#pragma unroll
            for (int fm = 0; fm < 4; ++fm)
#pragma unroll
                for (int fn = 0; fn < 4; ++fn)
                    acc[fm][fn] = __builtin_amdgcn_mfma_f32_16x16x32_bf16(
                        afr[fm], bfr[fn], acc[fm][fn], 0, 0, 0);
        }
        // fc1 epilogue -> LDS
#pragma unroll
        for (int fm = 0; fm < 4; ++fm) {
#pragma unroll
            for (int r = 0; r < 4; ++r) {
                int rr = fm * 16 + g * 4 + r;
#pragma unroll
                for (int fn = 0; fn < 4; ++fn) {
                    int col = colbase + fn * 16;
                    if (col < 168) {
                        float v = acc[fm][fn][r] + fc1b[col];
                        v = v * (bnfg[col] * BN_RSQ) + bnfb[col];
                        ts[rr][col] = fmaxf(v, 0.0f);
                    }
                }
            }
        }
    }
    __syncthreads();
    if (tid < 192) {
        int r = tid & 63, c = tid >> 6;
        float acc2 = fc2b[c];
#pragma unroll 4
        for (int k = 0; k < 168; ++k) acc2 += ts[r][k] * fc2W[k * 3 + c];
        int row = m0 + r;
        if (row < M) out[(size_t)row * 3 + c] = acc2;
    }
}

// ---------- degree histograms + edge-attr sums ----------
__global__ void edge_count(const int* __restrict__ e1d, const int* __restrict__ e2d,
                           const float* __restrict__ ef,
                           int* __restrict__ cnt1, int* __restrict__ cnt2,
                           float* __restrict__ easum, float* __restrict__ eaext, int E)
{
    int e = blockIdx.x * blockDim.x + threadIdx.x;
    if (e >= E) return;
    atomicAdd(&cnt1[e1d[e]], 1);
    int d2 = e2d[e];
    atomicAdd(&cnt2[d2], 1);
    float a = ef[e];
    atomicAdd(&easum[d2], a);
    eaext[e] = a;
}

__global__ void self_attr(const float* __restrict__ easum, const int* __restrict__ cnt2,
                          float* __restrict__ ea_loop, int N)
{
    int i = blockIdx.x * blockDim.x + threadIdx.x;
    if (i < N) ea_loop[i] = easum[i] / fmaxf((float)cnt2[i], 1.0f);
}

// ---------- exclusive scan (M <= 65536) ----------
__global__ void scan1(const int* __restrict__ cnt, int add1, int* __restrict__ excl,
                      int* __restrict__ bsum, int M)
{
    __shared__ int sh[SCAN_B];
    int i = blockIdx.x * SCAN_B + threadIdx.x;
    int v = (i < M) ? cnt[i] + add1 : 0;
    sh[threadIdx.x] = v;
    __syncthreads();
    for (int o = 1; o < SCAN_B; o <<= 1) {
        int t = (threadIdx.x >= o) ? sh[threadIdx.x - o] : 0;
        __syncthreads();
        sh[threadIdx.x] += t;
        __syncthreads();
    }
    if (i < M) excl[i] = sh[threadIdx.x] - v;
    if (threadIdx.x == SCAN_B - 1) bsum[blockIdx.x] = sh[threadIdx.x];
}

__global__ void scan2(int* __restrict__ bsum, int nb)
{
    __shared__ int sh[SCAN_B];
    int v = (threadIdx.x < nb) ? bsum[threadIdx.x] : 0;
    sh[threadIdx.x] = v;
    __syncthreads();
    for (int o = 1; o < SCAN_B; o <<= 1) {
        int t = (threadIdx.x >= o) ? sh[threadIdx.x - o] : 0;
        __syncthreads();
        sh[threadIdx.x] += t;
        __syncthreads();
    }
    if (threadIdx.x < nb) bsum[threadIdx.x] = sh[threadIdx.x] - v;  // exclusive
}

__global__ void scan3(int* __restrict__ excl, const int* __restrict__ bsum, int M)
{
    int i = blockIdx.x * SCAN_B + threadIdx.x;
    if (i < M) excl[i] += bsum[blockIdx.x];
}

// ---------- CSR fill ----------
__global__ void fill1(const int* __restrict__ e1s, const int* __restrict__ e1d,
                      const int* __restrict__ off1, int* __restrict__ cur1,
                      int* __restrict__ srcs1, int E)
{
    int e = blockIdx.x * blockDim.x + threadIdx.x;
    if (e >= E) return;
    int d = e1d[e];
    int pos = atomicAdd(&cur1[d], 1);
    srcs1[off1[d] + pos] = e1s[e];
}

__global__ void fill2(const int* __restrict__ e2d,
                      const int* __restrict__ off2, int* __restrict__ cur2,
                      int* __restrict__ eidx2, int E, int Eext)
{
    int t = blockIdx.x * blockDim.x + threadIdx.x;
    if (t >= Eext) return;
    int d = (t < E) ? e2d[t] : (t - E);
    int pos = atomicAdd(&cur2[d], 1);
    eidx2[off2[d] + pos] = t;
}

// ---------- SAGE: gather in projected 128-d space, fused epilogue into z ----------
__global__ void sage_gather(const int* __restrict__ srcs1, const int* __restrict__ off1,
                            const int* __restrict__ cnt1, const float* __restrict__ P,
                            const float* __restrict__ bl,
                            const float* __restrict__ bng, const float* __restrict__ bnb,
                            float* __restrict__ z, int N)
{
    int t = blockIdx.x * blockDim.x + threadIdx.x;
    if (t >= N * 32) return;
    int n = t >> 5, g = t & 31;
    int beg = off1[n], dg = cnt1[n];
    float4 acc = make_float4(0.f, 0.f, 0.f, 0.f);
    for (int j = beg; j < beg + dg; ++j) {
        int s = srcs1[j];
        float4 v = *reinterpret_cast<const float4*>(&P[(size_t)s * 256 + g * 4]);
        acc.x += v.x; acc.y += v.y; acc.z += v.z; acc.w += v.w;
    }
    float inv = 1.0f / fmaxf((float)dg, 1.0f);
    float a4[4] = {acc.x, acc.y, acc.z, acc.w};
#pragma unroll
    for (int k = 0; k < 4; ++k) {
        int c = g * 4 + k;
        float x = a4[k] * inv + bl[c] + P[(size_t)n * 256 + 128 + c];
        x = x * (bng[c] * BN_RSQ) + bnb[c];
        z[(size_t)n * 168 + c] = lrelu(x, 0.01f);
    }
}

// ---------- GATv2 linear projections ----------
template <int IND, int HC>
__global__ void gat_lin(const float* __restrict__ X,
                        const float* __restrict__ Wl, const float* __restrict__ bl,
                        const float* __restrict__ Wr, const float* __restrict__ br,
                        float* __restrict__ xl, float* __restrict__ xr, int N)
{
    int t = blockIdx.x * blockDim.x + threadIdx.x;
    if (t >= N * HC) return;
    int n = t / HC, j = t % HC;
    float al = bl[j], ar = br[j];
    const float* xrow = X + (size_t)n * IND;
#pragma unroll 4
    for (int k = 0; k < IND; ++k) {
        float xv = xrow[k];
        al += xv * Wl[k * HC + j];
        ar += xv * Wr[k * HC + j];
    }
    xl[t] = al;
    xr[t] = ar;
}

// ---------- fused GATv2 per (node, head) ----------
template <int H, int C, int MODE>
__global__ void gat_node(const int* __restrict__ eidx2, const int* __restrict__ off2,
                         const int* __restrict__ cnt2, const int* __restrict__ e2s,
                         const float* __restrict__ eaext,
                         const float* __restrict__ xl, const float* __restrict__ xr,
                         const float* __restrict__ We, const float* __restrict__ att,
                         const float* __restrict__ b,
                         const float* __restrict__ bng, const float* __restrict__ bnb,
                         float* __restrict__ slog, float* __restrict__ out,
                         int E, int N)
{
    int t = blockIdx.x * blockDim.x + threadIdx.x;
    if (t >= N * H) return;
    int n = t / H, h = t % H;

    float xrc[C], atth[C], weh[C];
#pragma unroll
    for (int c = 0; c < C; ++c) {
        xrc[c]  = xr[(size_t)n * (H * C) + h * C + c];
        atth[c] = att[h * C + c];
        weh[c]  = We[h * C + c];
    }

    const int beg = off2[n];
    const int dg = cnt2[n] + 1;  // + self loop

    float mx = -FLT_MAX;
    for (int jj = 0; jj < dg; ++jj) {
        int j = beg + jj;
        int e = eidx2[j];
        int s = (e < E) ? e2s[e] : (e - E);
        float ea = eaext[e];
        const float* xls = xl + (size_t)s * (H * C) + h * C;
        float acc = 0.0f;
#pragma unroll
        for (int c = 0; c < C; ++c) {
            float m = xls[c] + xrc[c] + ea * weh[c];
            acc += lrelu(m, 0.2f) * atth[c];
        }
        slog[(size_t)j * H + h] = acc;
        mx = fmaxf(mx, acc);
    }

    float den = 0.0f;
    float accv[C] = {};
    for (int jj = 0; jj < dg; ++jj) {
        int j = beg + jj;
        int e = eidx2[j];
        int s = (e < E) ? e2s[e] : (e - E);
        float ex = __expf(slog[(size_t)j * H + h] - mx);
        den += ex;
        const float* xls = xl + (size_t)s * (H * C) + h * C;
#pragma unroll
        for (int c = 0; c < C; ++c) accv[c] += ex * xls[c];
    }
    float inv = 1.0f / (den + 1e-16f);

#pragma unroll
    for (int c = 0; c < C; ++c) {
        int jch = h * C + c;
        float v = accv[c] * inv + b[jch];
        if (MODE == 1) {
            out[(size_t)n * (H * C) + jch] = lrelu(v, 0.01f);
        } else {
            v = v * (bng[jch] * BN_RSQ) + bnb[jch];
            out[(size_t)n * 168 + 128 + jch] = lrelu(v, 0.01f);
        }
    }
}

__global__ void copy_addf(const float* __restrict__ addf, float* __restrict__ z, int N)
{
    int t = blockIdx.x * blockDim.x + threadIdx.x;
    if (t >= N * 20) return;
    int n = t / 20, j = t % 20;
    z[(size_t)n * 168 + 148 + j] = addf[t];
}

// ---------- launch ----------
extern "C" void kernel_launch(void* const* d_in, const int* in_sizes, int n_in,
                              void* d_out, int out_size, void* d_ws, size_t ws_size,
                              hipStream_t stream)
{
    const float* features = (const float*)d_in[0];
    const int*   e1       = (const int*)d_in[1];
    const int*   e2       = (const int*)d_in[2];
    const float* ef       = (const float*)d_in[3];
    const float* addf     = (const float*)d_in[4];
    const float* sage_Wl  = (const float*)d_in[5];
    const float* sage_bl  = (const float*)d_in[6];
    const float* sage_Wr  = (const float*)d_in[7];
    const float* g1_Wl = (const float*)d_in[8];
    const float* g1_bl = (const float*)d_in[9];
    const float* g1_Wr = (const float*)d_in[10];
    const float* g1_br = (const float*)d_in[11];
    const float* g1_We = (const float*)d_in[12];
    const float* g1_att = (const float*)d_in[13];
    const float* g1_b = (const float*)d_in[14];
    const float* g2_Wl = (const float*)d_in[15];
    const float* g2_bl = (const float*)d_in[16];
    const float* g2_Wr = (const float*)d_in[17];
    const float* g2_br = (const float*)d_in[18];
    const float* g2_We = (const float*)d_in[19];
    const float* g2_att = (const float*)d_in[20];
    const float* g2_b = (const float*)d_in[21];
    const float* fc1_W = (const float*)d_in[22];
    const float* fc1_b = (const float*)d_in[23];
    const float* fc2_W = (const float*)d_in[24];
    const float* fc2_b = (const float*)d_in[25];
    const float* bnx_g = (const float*)d_in[26];
    const float* bnx_b = (const float*)d_in[27];
    const float* bny_g = (const float*)d_in[28];
    const float* bny_b = (const float*)d_in[29];
    const float* bnf_g = (const float*)d_in[30];
    const float* bnf_b = (const float*)d_in[31];

    const int N = in_sizes[0] / 1024;
    const int E = in_sizes[3];
    const int Eext = E + N;
    const int* e1s = e1, *e1d = e1 + E;
    const int* e2s = e2, *e2d = e2 + E;
    const int nb = (N + SCAN_B - 1) / SCAN_B;

    char* wb = (char*)d_ws;
    size_t off = 0;
    auto takeB = [&](size_t bytes) { char* p = wb + off; off = (off + bytes + 255) & ~(size_t)255; return p; };
    float* P     = (float*)takeB((size_t)N * 256 * 4);
    float* z     = (float*)takeB((size_t)N * 168 * 4);
    float* eaext = (float*)takeB((size_t)Eext * 4);
    float* easum = (float*)takeB((size_t)N * 4);
    float* xl1   = (float*)takeB((size_t)N * 40 * 4);
    float* xr1   = (float*)takeB((size_t)N * 40 * 4);
    float* y1    = (float*)takeB((size_t)N * 40 * 4);
    float* xl2   = (float*)takeB((size_t)N * 20 * 4);
    float* xr2   = (float*)takeB((size_t)N * 20 * 4);
    float* slog  = (float*)takeB((size_t)Eext * 4 * 4);
    unsigned short* Bt  = (unsigned short*)takeB((size_t)256 * 1024 * 2);
    unsigned short* Bt1 = (unsigned short*)takeB((size_t)192 * 192 * 2);
    int* cnt1  = (int*)takeB((size_t)N * 4);
    int* cnt2  = (int*)takeB((size_t)N * 4);
    int* cur1  = (int*)takeB((size_t)N * 4);
    int* cur2  = (int*)takeB((size_t)N * 4);
    int* off1  = (int*)takeB((size_t)N * 4);
    int* off2  = (int*)takeB((size_t)N * 4);
    int* bsum1 = (int*)takeB(SCAN_B * 4);
    int* bsum2 = (int*)takeB(SCAN_B * 4);
    int* srcs1 = (int*)takeB((size_t)E * 4);
    int* eidx2 = (int*)takeB((size_t)Eext * 4);

    hipMemsetAsync(cnt1, 0, (size_t)N * 4, stream);
    hipMemsetAsync(cnt2, 0, (size_t)N * 4, stream);
    hipMemsetAsync(cur1, 0, (size_t)N * 4, stream);
    hipMemsetAsync(cur2, 0, (size_t)N * 4, stream);
    hipMemsetAsync(easum, 0, (size_t)N * 4, stream);

    const int B = 256;
    // weight prep
    conv_wsage<<<(256 * 1024 + B - 1) / B, B, 0, stream>>>(sage_Wl, sage_Wr, Bt);
    conv_wfc1<<<(192 * 192 + B - 1) / B, B, 0, stream>>>(fc1_W, Bt1);

    // histograms + edge attrs
    edge_count<<<(E + B - 1) / B, B, 0, stream>>>(e1d, e2d, ef, cnt1, cnt2, easum, eaext, E);
    self_attr<<<(N + B - 1) / B, B, 0, stream>>>(easum, cnt2, eaext + E, N);

    // CSR offsets
    scan1<<<nb, SCAN_B, 0, stream>>>(cnt1, 0, off1, bsum1, N);
    scan2<<<1, SCAN_B, 0, stream>>>(bsum1, nb);
    scan3<<<nb, SCAN_B, 0, stream>>>(off1, bsum1, N);
    scan1<<<nb, SCAN_B, 0, stream>>>(cnt2, 1, off2, bsum2, N);
    scan2<<<1, SCAN_B, 0, stream>>>(bsum2, nb);
    scan3<<<nb, SCAN_B, 0, stream>>>(off2, bsum2, N);

    // CSR fill
    fill1<<<(E + B - 1) / B, B, 0, stream>>>(e1s, e1d, off1, cur1, srcs1, E);
    fill2<<<(Eext + B - 1) / B, B, 0, stream>>>(e2d, off2, cur2, eidx2, E, Eext);

    // SAGE
    const int mtiles = (N + 63) / 64;
    gemm_sage_mfma<<<mtiles, 256, 0, stream>>>(features, Bt, P, N);
    sage_gather<<<(N * 32 + B - 1) / B, B, 0, stream>>>(srcs1, off1, cnt1, P, sage_bl, bnx_g, bnx_b, z, N);

    // GAT layer 1 (20 -> 4x10)
    gat_lin<20, 40><<<(N * 40 + B - 1) / B, B, 0, stream>>>(addf, g1_Wl, g1_bl, g1_Wr, g1_br, xl1, xr1, N);
    gat_node<4, 10, 1><<<(N * 4 + B - 1) / B, B, 0, stream>>>(
        eidx2, off2, cnt2, e2s, eaext, xl1, xr1, g1_We, g1_att, g1_b,
        nullptr, nullptr, slog, y1, E, N);

    // GAT layer 2 (40 -> 4x5)
    gat_lin<40, 20><<<(N * 20 + B - 1) / B, B, 0, stream>>>(y1, g2_Wl, g2_bl, g2_Wr, g2_br, xl2, xr2, N);
    gat_node<4, 5, 2><<<(N * 4 + B - 1) / B, B, 0, stream>>>(
        eidx2, off2, cnt2, e2s, eaext, xl2, xr2, g2_We, g2_att, g2_b,
        bny_g, bny_b, slog, z, E, N);

    copy_addf<<<(N * 20 + B - 1) / B, B, 0, stream>>>(addf, z, N);

    // MLP head (fc1 MFMA + fc2 fused)
    mlp_mfma<<<mtiles, 256, 0, stream>>>(z, Bt1, fc1_b, bnf_g, bnf_b, fc2_W, fc2_b, (float*)d_out, N);
}

// Round 4
// 389.553 us; speedup vs baseline: 6.1235x; 1.2910x over previous
//
#include <hip/hip_runtime.h>
#include <hip/hip_bf16.h>
#include <cfloat>

__device__ __forceinline__ float lrelu(float x, float a) { return x > 0.0f ? x : a * x; }

// fp32 -> bf16 round-to-nearest-even (bit pattern)
__device__ __forceinline__ unsigned short f2bf(float f) {
    unsigned u = __float_as_uint(f);
    unsigned r = (u + 0x7FFFu + ((u >> 16) & 1u)) >> 16;
    return (unsigned short)r;
}

typedef __attribute__((ext_vector_type(8))) short short8;
typedef __attribute__((ext_vector_type(4))) float f32x4;

#define BN_RSQ 0.99999500003749968750f  // 1/sqrt(1+1e-5)
#define SCAN_B 256

// ---------- weight conversion into MFMA fragment-order (coalesced) layouts ----------
// Btp layout: [((kstep*4 + wid)*4 + fn)*64 + lane] of short8
//   c = wid*64 + fn*16 + (lane&15);  k = kstep*32 + (lane>>4)*8 + j
__global__ void conv_wsage(const float* __restrict__ Wl, const float* __restrict__ Wr,
                           unsigned short* __restrict__ Btp)
{
    int idx = blockIdx.x * blockDim.x + threadIdx.x;
    if (idx >= 256 * 1024) return;
    int j    = idx & 7;
    int lane = (idx >> 3) & 63;
    int fn   = (idx >> 9) & 3;
    int wid  = (idx >> 11) & 3;
    int t    = idx >> 13;                    // kstep 0..31
    int c = wid * 64 + fn * 16 + (lane & 15);
    int k = t * 32 + (lane >> 4) * 8 + j;
    float v = (c < 128) ? Wl[(size_t)k * 128 + c] : Wr[(size_t)k * 128 + (c - 128)];
    Btp[idx] = f2bf(v);
}

// Bt1p layout: [(((t*3 + wid)*4 + fn)*64 + lane)*8 + j], t in [0,6), wid in [0,3)
__global__ void conv_wfc1(const float* __restrict__ fc1W, unsigned short* __restrict__ Bt1p)
{
    int idx = blockIdx.x * blockDim.x + threadIdx.x;
    if (idx >= 36864) return;
    int j    = idx & 7;
    int lane = (idx >> 3) & 63;
    int fn   = (idx >> 9) & 3;
    int q    = idx >> 11;                    // t*3 + wid, 0..17
    int wid = q % 3, t = q / 3;
    int c = wid * 64 + fn * 16 + (lane & 15);
    int k = t * 32 + (lane >> 4) * 8 + j;
    float v = (c < 168 && k < 168) ? fc1W[(size_t)k * 168 + c] : 0.0f;
    Bt1p[idx] = f2bf(v);
}

// ---------- SAGE GEMM via MFMA: P = features @ [Wl|Wr], [M,1024]x[1024,256] ----------
// block: 64 rows x 256 cols, 4 waves (each 64x64 = 4x4 fragments of 16x16).
// A staged via LDS (coalesced + bf16-converted), double-buffered, 1 barrier/chunk.
__global__ __launch_bounds__(256) void gemm_sage_mfma(
    const float* __restrict__ A, const unsigned short* __restrict__ Btp,
    float* __restrict__ P, int M)
{
    __shared__ unsigned short As2[2][64][72];   // +8 bf16 pad -> 2-way (free) on ds_read_b128
    const int tid = threadIdx.x;
    const int wid = tid >> 6, lane = tid & 63;
    const int m0 = blockIdx.x * 64;
    const int l16 = lane & 15, g = lane >> 4;
    const int colbase = wid * 64 + l16;
    const short8* Bv = reinterpret_cast<const short8*>(Btp);

    f32x4 acc[4][4] = {};

    // stage chunk 0
#pragma unroll
    for (int p = 0; p < 4; ++p) {
        int flat = p * 1024 + tid * 4;
        int row = flat >> 6, col = flat & 63;
        int ar = m0 + row;
        float4 v = make_float4(0.f, 0.f, 0.f, 0.f);
        if (ar < M) v = *reinterpret_cast<const float4*>(&A[(size_t)ar * 1024 + col]);
        ushort4 u;
        u.x = f2bf(v.x); u.y = f2bf(v.y); u.z = f2bf(v.z); u.w = f2bf(v.w);
        *reinterpret_cast<ushort4*>(&As2[0][row][col]) = u;
    }
    __syncthreads();

    for (int c = 0; c < 16; ++c) {
        const int buf = c & 1;
        float4 nf[4];
        if (c < 15) {
            const int k0 = (c + 1) * 64;
#pragma unroll
            for (int p = 0; p < 4; ++p) {
                int flat = p * 1024 + tid * 4;
                int row = flat >> 6, col = flat & 63;
                int ar = m0 + row;
                nf[p] = make_float4(0.f, 0.f, 0.f, 0.f);
                if (ar < M) nf[p] = *reinterpret_cast<const float4*>(&A[(size_t)ar * 1024 + k0 + col]);
            }
        }
#pragma unroll
        for (int t = 0; t < 2; ++t) {
            const int ks = c * 2 + t;   // global k-step 0..31
            short8 afr[4];
#pragma unroll
            for (int fm = 0; fm < 4; ++fm)
                afr[fm] = *reinterpret_cast<const short8*>(&As2[buf][fm * 16 + l16][t * 32 + g * 8]);
            short8 bfr[4];
#pragma unroll
            for (int fn = 0; fn < 4; ++fn)
                bfr[fn] = Bv[((ks * 4 + wid) * 4 + fn) * 64 + lane];
#pragma unroll
            for (int fm = 0; fm < 4; ++fm)
#pragma unroll
                for (int fn = 0; fn < 4; ++fn)
                    acc[fm][fn] = __builtin_amdgcn_mfma_f32_16x16x32_bf16(
                        afr[fm], bfr[fn], acc[fm][fn], 0, 0, 0);
        }
        if (c < 15) {
#pragma unroll
            for (int p = 0; p < 4; ++p) {
                int flat = p * 1024 + tid * 4;
                int row = flat >> 6, col = flat & 63;
                ushort4 u;
                u.x = f2bf(nf[p].x); u.y = f2bf(nf[p].y);
                u.z = f2bf(nf[p].z); u.w = f2bf(nf[p].w);
                *reinterpret_cast<ushort4*>(&As2[buf ^ 1][row][col]) = u;
            }
        }
        __syncthreads();
    }

#pragma unroll
    for (int fm = 0; fm < 4; ++fm) {
#pragma unroll
        for (int r = 0; r < 4; ++r) {
            int row = m0 + fm * 16 + g * 4 + r;
            if (row < M) {
#pragma unroll
                for (int fn = 0; fn < 4; ++fn)
                    P[(size_t)row * 256 + colbase + fn * 16] = acc[fm][fn][r];
            }
        }
    }
}

// ---------- MLP head via MFMA ----------
// stage z-tile -> LDS bf16 [64][200] (zero-padded); fc1 MFMA (3 waves); ts overlays zs; fc2 fused.
__global__ __launch_bounds__(256) void mlp_mfma(
    const float* __restrict__ z, const unsigned short* __restrict__ Bt1p,
    const float* __restrict__ fc1b, const float* __restrict__ bnfg, const float* __restrict__ bnfb,
    const float* __restrict__ fc2W, const float* __restrict__ fc2b,
    float* __restrict__ out, int M)
{
    __shared__ char smem[64 * 169 * 4];
    unsigned short (*zs)[200] = reinterpret_cast<unsigned short(*)[200]>(smem);
    float (*ts)[169] = reinterpret_cast<float(*)[169]>(smem);
    const int tid = threadIdx.x;
    const int wid = tid >> 6, lane = tid & 63;
    const int m0 = blockIdx.x * 64;
    const int l16 = lane & 15, g = lane >> 4;
    const short8* Bv = reinterpret_cast<const short8*>(Bt1p);

    // stage (64 rows x 200 cols, cols>=168 and OOB rows zero)
#pragma unroll
    for (int p = 0; p < 13; ++p) {
        int idx = p * 256 + tid;
        if (idx < 3200) {
            int row = idx / 50, c4 = (idx % 50) * 4;
            int ar = m0 + row;
            float4 v = make_float4(0.f, 0.f, 0.f, 0.f);
            if (ar < M && c4 < 168)
                v = *reinterpret_cast<const float4*>(&z[(size_t)ar * 168 + c4]);
            ushort4 u;
            u.x = f2bf(v.x); u.y = f2bf(v.y); u.z = f2bf(v.z); u.w = f2bf(v.w);
            *reinterpret_cast<ushort4*>(&zs[row][c4]) = u;
        }
    }
    __syncthreads();

    f32x4 acc[4][4] = {};
    if (wid < 3) {
#pragma unroll
        for (int t = 0; t < 6; ++t) {
            short8 afr[4];
#pragma unroll
            for (int fm = 0; fm < 4; ++fm)
                afr[fm] = *reinterpret_cast<const short8*>(&zs[fm * 16 + l16][t * 32 + g * 8]);
            short8 bfr[4];
#pragma unroll
            for (int fn = 0; fn < 4; ++fn)
                bfr[fn] = Bv[((t * 3 + wid) * 4 + fn) * 64 + lane];
#pragma unroll
            for (int fm = 0; fm < 4; ++fm)
#pragma unroll
                for (int fn = 0; fn < 4; ++fn)
                    acc[fm][fn] = __builtin_amdgcn_mfma_f32_16x16x32_bf16(
                        afr[fm], bfr[fn], acc[fm][fn], 0, 0, 0);
        }
    }
    __syncthreads();   // all zs reads done before ts overlay
    if (wid < 3) {
        const int colbase = wid * 64 + l16;
#pragma unroll
        for (int fm = 0; fm < 4; ++fm) {
#pragma unroll
            for (int r = 0; r < 4; ++r) {
                int rr = fm * 16 + g * 4 + r;
#pragma unroll
                for (int fn = 0; fn < 4; ++fn) {
                    int col = colbase + fn * 16;
                    if (col < 168) {
                        float v = acc[fm][fn][r] + fc1b[col];
                        v = v * (bnfg[col] * BN_RSQ) + bnfb[col];
                        ts[rr][col] = fmaxf(v, 0.0f);
                    }
                }
            }
        }
    }
    __syncthreads();
    if (tid < 192) {
        int r = tid & 63, c = tid >> 6;
        float acc2 = fc2b[c];
#pragma unroll 4
        for (int k = 0; k < 168; ++k) acc2 += ts[r][k] * fc2W[k * 3 + c];
        int row = m0 + r;
        if (row < M) out[(size_t)row * 3 + c] = acc2;
    }
}

// ---------- degree histograms + edge-attr sums ----------
__global__ void edge_count(const int* __restrict__ e1d, const int* __restrict__ e2d,
                           const float* __restrict__ ef,
                           int* __restrict__ cnt1, int* __restrict__ cnt2,
                           float* __restrict__ easum, float* __restrict__ eaext, int E)
{
    int e = blockIdx.x * blockDim.x + threadIdx.x;
    if (e >= E) return;
    atomicAdd(&cnt1[e1d[e]], 1);
    int d2 = e2d[e];
    atomicAdd(&cnt2[d2], 1);
    float a = ef[e];
    atomicAdd(&easum[d2], a);
    eaext[e] = a;
}

__global__ void self_attr(const float* __restrict__ easum, const int* __restrict__ cnt2,
                          float* __restrict__ ea_loop, int N)
{
    int i = blockIdx.x * blockDim.x + threadIdx.x;
    if (i < N) ea_loop[i] = easum[i] / fmaxf((float)cnt2[i], 1.0f);
}

// ---------- exclusive scan (M <= 65536) ----------
__global__ void scan1(const int* __restrict__ cnt, int add1, int* __restrict__ excl,
                      int* __restrict__ bsum, int M)
{
    __shared__ int sh[SCAN_B];
    int i = blockIdx.x * SCAN_B + threadIdx.x;
    int v = (i < M) ? cnt[i] + add1 : 0;
    sh[threadIdx.x] = v;
    __syncthreads();
    for (int o = 1; o < SCAN_B; o <<= 1) {
        int t = (threadIdx.x >= o) ? sh[threadIdx.x - o] : 0;
        __syncthreads();
        sh[threadIdx.x] += t;
        __syncthreads();
    }
    if (i < M) excl[i] = sh[threadIdx.x] - v;
    if (threadIdx.x == SCAN_B - 1) bsum[blockIdx.x] = sh[threadIdx.x];
}

__global__ void scan2(int* __restrict__ bsum, int nb)
{
    __shared__ int sh[SCAN_B];
    int v = (threadIdx.x < nb) ? bsum[threadIdx.x] : 0;
    sh[threadIdx.x] = v;
    __syncthreads();
    for (int o = 1; o < SCAN_B; o <<= 1) {
        int t = (threadIdx.x >= o) ? sh[threadIdx.x - o] : 0;
        __syncthreads();
        sh[threadIdx.x] += t;
        __syncthreads();
    }
    if (threadIdx.x < nb) bsum[threadIdx.x] = sh[threadIdx.x] - v;  // exclusive
}

__global__ void scan3(int* __restrict__ excl, const int* __restrict__ bsum, int M)
{
    int i = blockIdx.x * SCAN_B + threadIdx.x;
    if (i < M) excl[i] += bsum[blockIdx.x];
}

// ---------- CSR fill ----------
__global__ void fill1(const int* __restrict__ e1s, const int* __restrict__ e1d,
                      const int* __restrict__ off1, int* __restrict__ cur1,
                      int* __restrict__ srcs1, int E)
{
    int e = blockIdx.x * blockDim.x + threadIdx.x;
    if (e >= E) return;
    int d = e1d[e];
    int pos = atomicAdd(&cur1[d], 1);
    srcs1[off1[d] + pos] = e1s[e];
}

__global__ void fill2(const int* __restrict__ e2d,
                      const int* __restrict__ off2, int* __restrict__ cur2,
                      int* __restrict__ eidx2, int E, int Eext)
{
    int t = blockIdx.x * blockDim.x + threadIdx.x;
    if (t >= Eext) return;
    int d = (t < E) ? e2d[t] : (t - E);
    int pos = atomicAdd(&cur2[d], 1);
    eidx2[off2[d] + pos] = t;
}

// ---------- SAGE: gather in projected 128-d space, fused epilogue into z ----------
__global__ void sage_gather(const int* __restrict__ srcs1, const int* __restrict__ off1,
                            const int* __restrict__ cnt1, const float* __restrict__ P,
                            const float* __restrict__ bl,
                            const float* __restrict__ bng, const float* __restrict__ bnb,
                            float* __restrict__ z, int N)
{
    int t = blockIdx.x * blockDim.x + threadIdx.x;
    if (t >= N * 32) return;
    int n = t >> 5, g = t & 31;
    int beg = off1[n], dg = cnt1[n];
    float4 acc = make_float4(0.f, 0.f, 0.f, 0.f);
    for (int j = beg; j < beg + dg; ++j) {
        int s = srcs1[j];
        float4 v = *reinterpret_cast<const float4*>(&P[(size_t)s * 256 + g * 4]);
        acc.x += v.x; acc.y += v.y; acc.z += v.z; acc.w += v.w;
    }
    float inv = 1.0f / fmaxf((float)dg, 1.0f);
    float a4[4] = {acc.x, acc.y, acc.z, acc.w};
#pragma unroll
    for (int k = 0; k < 4; ++k) {
        int c = g * 4 + k;
        float x = a4[k] * inv + bl[c] + P[(size_t)n * 256 + 128 + c];
        x = x * (bng[c] * BN_RSQ) + bnb[c];
        z[(size_t)n * 168 + c] = lrelu(x, 0.01f);
    }
}

// ---------- GATv2 linear projections ----------
template <int IND, int HC>
__global__ void gat_lin(const float* __restrict__ X,
                        const float* __restrict__ Wl, const float* __restrict__ bl,
                        const float* __restrict__ Wr, const float* __restrict__ br,
                        float* __restrict__ xl, float* __restrict__ xr, int N)
{
    int t = blockIdx.x * blockDim.x + threadIdx.x;
    if (t >= N * HC) return;
    int n = t / HC, j = t % HC;
    float al = bl[j], ar = br[j];
    const float* xrow = X + (size_t)n * IND;
#pragma unroll 4
    for (int k = 0; k < IND; ++k) {
        float xv = xrow[k];
        al += xv * Wl[k * HC + j];
        ar += xv * Wr[k * HC + j];
    }
    xl[t] = al;
    xr[t] = ar;
}

// ---------- fused GATv2 per (node, head) ----------
template <int H, int C, int MODE>
__global__ void gat_node(const int* __restrict__ eidx2, const int* __restrict__ off2,
                         const int* __restrict__ cnt2, const int* __restrict__ e2s,
                         const float* __restrict__ eaext,
                         const float* __restrict__ xl, const float* __restrict__ xr,
                         const float* __restrict__ We, const float* __restrict__ att,
                         const float* __restrict__ b,
                         const float* __restrict__ bng, const float* __restrict__ bnb,
                         float* __restrict__ slog, float* __restrict__ out,
                         int E, int N)
{
    int t = blockIdx.x * blockDim.x + threadIdx.x;
    if (t >= N * H) return;
    int n = t / H, h = t % H;

    float xrc[C], atth[C], weh[C];
#pragma unroll
    for (int c = 0; c < C; ++c) {
        xrc[c]  = xr[(size_t)n * (H * C) + h * C + c];
        atth[c] = att[h * C + c];
        weh[c]  = We[h * C + c];
    }

    const int beg = off2[n];
    const int dg = cnt2[n] + 1;  // + self loop

    float mx = -FLT_MAX;
    for (int jj = 0; jj < dg; ++jj) {
        int j = beg + jj;
        int e = eidx2[j];
        int s = (e < E) ? e2s[e] : (e - E);
        float ea = eaext[e];
        const float* xls = xl + (size_t)s * (H * C) + h * C;
        float acc = 0.0f;
#pragma unroll
        for (int c = 0; c < C; ++c) {
            float m = xls[c] + xrc[c] + ea * weh[c];
            acc += lrelu(m, 0.2f) * atth[c];
        }
        slog[(size_t)j * H + h] = acc;
        mx = fmaxf(mx, acc);
    }

    float den = 0.0f;
    float accv[C] = {};
    for (int jj = 0; jj < dg; ++jj) {
        int j = beg + jj;
        int e = eidx2[j];
        int s = (e < E) ? e2s[e] : (e - E);
        float ex = __expf(slog[(size_t)j * H + h] - mx);
        den += ex;
        const float* xls = xl + (size_t)s * (H * C) + h * C;
#pragma unroll
        for (int c = 0; c < C; ++c) accv[c] += ex * xls[c];
    }
    float inv = 1.0f / (den + 1e-16f);

#pragma unroll
    for (int c = 0; c < C; ++c) {
        int jch = h * C + c;
        float v = accv[c] * inv + b[jch];
        if (MODE == 1) {
            out[(size_t)n * (H * C) + jch] = lrelu(v, 0.01f);
        } else {
            v = v * (bng[jch] * BN_RSQ) + bnb[jch];
            out[(size_t)n * 168 + 128 + jch] = lrelu(v, 0.01f);
        }
    }
}

__global__ void copy_addf(const float* __restrict__ addf, float* __restrict__ z, int N)
{
    int t = blockIdx.x * blockDim.x + threadIdx.x;
    if (t >= N * 20) return;
    int n = t / 20, j = t % 20;
    z[(size_t)n * 168 + 148 + j] = addf[t];
}

// ---------- launch ----------
extern "C" void kernel_launch(void* const* d_in, const int* in_sizes, int n_in,
                              void* d_out, int out_size, void* d_ws, size_t ws_size,
                              hipStream_t stream)
{
    const float* features = (const float*)d_in[0];
    const int*   e1       = (const int*)d_in[1];
    const int*   e2       = (const int*)d_in[2];
    const float* ef       = (const float*)d_in[3];
    const float* addf     = (const float*)d_in[4];
    const float* sage_Wl  = (const float*)d_in[5];
    const float* sage_bl  = (const float*)d_in[6];
    const float* sage_Wr  = (const float*)d_in[7];
    const float* g1_Wl = (const float*)d_in[8];
    const float* g1_bl = (const float*)d_in[9];
    const float* g1_Wr = (const float*)d_in[10];
    const float* g1_br = (const float*)d_in[11];
    const float* g1_We = (const float*)d_in[12];
    const float* g1_att = (const float*)d_in[13];
    const float* g1_b = (const float*)d_in[14];
    const float* g2_Wl = (const float*)d_in[15];
    const float* g2_bl = (const float*)d_in[16];
    const float* g2_Wr = (const float*)d_in[17];
    const float* g2_br = (const float*)d_in[18];
    const float* g2_We = (const float*)d_in[19];
    const float* g2_att = (const float*)d_in[20];
    const float* g2_b = (const float*)d_in[21];
    const float* fc1_W = (const float*)d_in[22];
    const float* fc1_b = (const float*)d_in[23];
    const float* fc2_W = (const float*)d_in[24];
    const float* fc2_b = (const float*)d_in[25];
    const float* bnx_g = (const float*)d_in[26];
    const float* bnx_b = (const float*)d_in[27];
    const float* bny_g = (const float*)d_in[28];
    const float* bny_b = (const float*)d_in[29];
    const float* bnf_g = (const float*)d_in[30];
    const float* bnf_b = (const float*)d_in[31];

    const int N = in_sizes[0] / 1024;
    const int E = in_sizes[3];
    const int Eext = E + N;
    const int* e1s = e1, *e1d = e1 + E;
    const int* e2s = e2, *e2d = e2 + E;
    const int nb = (N + SCAN_B - 1) / SCAN_B;

    char* wb = (char*)d_ws;
    size_t off = 0;
    auto takeB = [&](size_t bytes) { char* p = wb + off; off = (off + bytes + 255) & ~(size_t)255; return p; };
    float* P     = (float*)takeB((size_t)N * 256 * 4);
    float* z     = (float*)takeB((size_t)N * 168 * 4);
    float* eaext = (float*)takeB((size_t)Eext * 4);
    float* easum = (float*)takeB((size_t)N * 4);
    float* xl1   = (float*)takeB((size_t)N * 40 * 4);
    float* xr1   = (float*)takeB((size_t)N * 40 * 4);
    float* y1    = (float*)takeB((size_t)N * 40 * 4);
    float* xl2   = (float*)takeB((size_t)N * 20 * 4);
    float* xr2   = (float*)takeB((size_t)N * 20 * 4);
    float* slog  = (float*)takeB((size_t)Eext * 4 * 4);
    unsigned short* Btp  = (unsigned short*)takeB((size_t)256 * 1024 * 2);
    unsigned short* Bt1p = (unsigned short*)takeB((size_t)36864 * 2);
    int* cnt1  = (int*)takeB((size_t)N * 4);
    int* cnt2  = (int*)takeB((size_t)N * 4);
    int* cur1  = (int*)takeB((size_t)N * 4);
    int* cur2  = (int*)takeB((size_t)N * 4);
    int* off1  = (int*)takeB((size_t)N * 4);
    int* off2  = (int*)takeB((size_t)N * 4);
    int* bsum1 = (int*)takeB(SCAN_B * 4);
    int* bsum2 = (int*)takeB(SCAN_B * 4);
    int* srcs1 = (int*)takeB((size_t)E * 4);
    int* eidx2 = (int*)takeB((size_t)Eext * 4);

    hipMemsetAsync(cnt1, 0, (size_t)N * 4, stream);
    hipMemsetAsync(cnt2, 0, (size_t)N * 4, stream);
    hipMemsetAsync(cur1, 0, (size_t)N * 4, stream);
    hipMemsetAsync(cur2, 0, (size_t)N * 4, stream);
    hipMemsetAsync(easum, 0, (size_t)N * 4, stream);

    const int B = 256;
    // weight prep (fragment-order layouts)
    conv_wsage<<<(256 * 1024 + B - 1) / B, B, 0, stream>>>(sage_Wl, sage_Wr, Btp);
    conv_wfc1<<<(36864 + B - 1) / B, B, 0, stream>>>(fc1_W, Bt1p);

    // histograms + edge attrs
    edge_count<<<(E + B - 1) / B, B, 0, stream>>>(e1d, e2d, ef, cnt1, cnt2, easum, eaext, E);
    self_attr<<<(N + B - 1) / B, B, 0, stream>>>(easum, cnt2, eaext + E, N);

    // CSR offsets
    scan1<<<nb, SCAN_B, 0, stream>>>(cnt1, 0, off1, bsum1, N);
    scan2<<<1, SCAN_B, 0, stream>>>(bsum1, nb);
    scan3<<<nb, SCAN_B, 0, stream>>>(off1, bsum1, N);
    scan1<<<nb, SCAN_B, 0, stream>>>(cnt2, 1, off2, bsum2, N);
    scan2<<<1, SCAN_B, 0, stream>>>(bsum2, nb);
    scan3<<<nb, SCAN_B, 0, stream>>>(off2, bsum2, N);

    // CSR fill
    fill1<<<(E + B - 1) / B, B, 0, stream>>>(e1s, e1d, off1, cur1, srcs1, E);
    fill2<<<(Eext + B - 1) / B, B, 0, stream>>>(e2d, off2, cur2, eidx2, E, Eext);

    // SAGE
    const int mtiles = (N + 63) / 64;
    gemm_sage_mfma<<<mtiles, 256, 0, stream>>>(features, Btp, P, N);
    sage_gather<<<(N * 32 + B - 1) / B, B, 0, stream>>>(srcs1, off1, cnt1, P, sage_bl, bnx_g, bnx_b, z, N);

    // GAT layer 1 (20 -> 4x10)
    gat_lin<20, 40><<<(N * 40 + B - 1) / B, B, 0, stream>>>(addf, g1_Wl, g1_bl, g1_Wr, g1_br, xl1, xr1, N);
    gat_node<4, 10, 1><<<(N * 4 + B - 1) / B, B, 0, stream>>>(
        eidx2, off2, cnt2, e2s, eaext, xl1, xr1, g1_We, g1_att, g1_b,
        nullptr, nullptr, slog, y1, E, N);

    // GAT layer 2 (40 -> 4x5)
    gat_lin<40, 20><<<(N * 20 + B - 1) / B, B, 0, stream>>>(y1, g2_Wl, g2_bl, g2_Wr, g2_br, xl2, xr2, N);
    gat_node<4, 5, 2><<<(N * 4 + B - 1) / B, B, 0, stream>>>(
        eidx2, off2, cnt2, e2s, eaext, xl2, xr2, g2_We, g2_att, g2_b,
        bny_g, bny_b, slog, z, E, N);

    copy_addf<<<(N * 20 + B - 1) / B, B, 0, stream>>>(addf, z, N);

    // MLP head (fc1 MFMA + fc2 fused)
    mlp_mfma<<<mtiles, 256, 0, stream>>>(z, Bt1p, fc1_b, bnf_g, bnf_b, fc2_W, fc2_b, (float*)d_out, N);
}

// Round 5
// 319.130 us; speedup vs baseline: 7.4748x; 1.2207x over previous
//
#include <hip/hip_runtime.h>
#include <hip/hip_bf16.h>
#include <cfloat>

__device__ __forceinline__ float lrelu(float x, float a) { return x > 0.0f ? x : a * x; }

// fp32 -> bf16 round-to-nearest-even (bit pattern)
__device__ __forceinline__ unsigned short f2bf(float f) {
    unsigned u = __float_as_uint(f);
    unsigned r = (u + 0x7FFFu + ((u >> 16) & 1u)) >> 16;
    return (unsigned short)r;
}
__device__ __forceinline__ float bf2f(unsigned short u) {
    return __uint_as_float((unsigned)u << 16);
}

typedef __attribute__((ext_vector_type(8))) short short8;
typedef __attribute__((ext_vector_type(4))) float f32x4;

#define BN_RSQ 0.99999500003749968750f  // 1/sqrt(1+1e-5)
#define SCAN_B 256

// ---------- weight conversion into MFMA fragment-order (coalesced) layouts ----------
__global__ void conv_wsage(const float* __restrict__ Wl, const float* __restrict__ Wr,
                           unsigned short* __restrict__ Btp)
{
    int idx = blockIdx.x * blockDim.x + threadIdx.x;
    if (idx >= 256 * 1024) return;
    int j    = idx & 7;
    int lane = (idx >> 3) & 63;
    int fn   = (idx >> 9) & 3;
    int wid  = (idx >> 11) & 3;
    int t    = idx >> 13;                    // kstep 0..31
    int c = wid * 64 + fn * 16 + (lane & 15);
    int k = t * 32 + (lane >> 4) * 8 + j;
    float v = (c < 128) ? Wl[(size_t)k * 128 + c] : Wr[(size_t)k * 128 + (c - 128)];
    Btp[idx] = f2bf(v);
}

__global__ void conv_wfc1(const float* __restrict__ fc1W, unsigned short* __restrict__ Bt1p)
{
    int idx = blockIdx.x * blockDim.x + threadIdx.x;
    if (idx >= 36864) return;
    int j    = idx & 7;
    int lane = (idx >> 3) & 63;
    int fn   = (idx >> 9) & 3;
    int q    = idx >> 11;                    // t*3 + wid, 0..17
    int wid = q % 3, t = q / 3;
    int c = wid * 64 + fn * 16 + (lane & 15);
    int k = t * 32 + (lane >> 4) * 8 + j;
    float v = (c < 168 && k < 168) ? fc1W[(size_t)k * 168 + c] : 0.0f;
    Bt1p[idx] = f2bf(v);
}

// ---------- SAGE GEMM via MFMA, 2-deep prefetch pipeline, bf16 P output ----------
__global__ __launch_bounds__(256) void gemm_sage_mfma(
    const float* __restrict__ A, const unsigned short* __restrict__ Btp,
    unsigned short* __restrict__ P, int M)
{
    __shared__ unsigned short As2[2][64][72];
    const int tid = threadIdx.x;
    const int wid = tid >> 6, lane = tid & 63;
    const int m0 = blockIdx.x * 64;
    const int l16 = lane & 15, g = lane >> 4;
    const int colbase = wid * 64 + l16;
    const short8* Bv = reinterpret_cast<const short8*>(Btp);
    const int srow = tid >> 4, scol = (tid & 15) * 4;

    f32x4 acc[4][4] = {};
    float4 rcur[4], rnext[4];

    // prolog: chunk0 -> LDS0; chunk1 -> rcur
#pragma unroll
    for (int p = 0; p < 4; ++p) {
        int ar = m0 + p * 16 + srow;
        rcur[p] = make_float4(0.f, 0.f, 0.f, 0.f);
        if (ar < M) rcur[p] = *reinterpret_cast<const float4*>(&A[(size_t)ar * 1024 + scol]);
    }
#pragma unroll
    for (int p = 0; p < 4; ++p) {
        ushort4 u;
        u.x = f2bf(rcur[p].x); u.y = f2bf(rcur[p].y); u.z = f2bf(rcur[p].z); u.w = f2bf(rcur[p].w);
        *reinterpret_cast<ushort4*>(&As2[0][p * 16 + srow][scol]) = u;
    }
#pragma unroll
    for (int p = 0; p < 4; ++p) {
        int ar = m0 + p * 16 + srow;
        rcur[p] = make_float4(0.f, 0.f, 0.f, 0.f);
        if (ar < M) rcur[p] = *reinterpret_cast<const float4*>(&A[(size_t)ar * 1024 + 64 + scol]);
    }
    __syncthreads();

    for (int c = 0; c < 16; ++c) {
        const int buf = c & 1;
        if (c < 14) {
            const int k0 = (c + 2) * 64;
#pragma unroll
            for (int p = 0; p < 4; ++p) {
                int ar = m0 + p * 16 + srow;
                rnext[p] = make_float4(0.f, 0.f, 0.f, 0.f);
                if (ar < M) rnext[p] = *reinterpret_cast<const float4*>(&A[(size_t)ar * 1024 + k0 + scol]);
            }
        }
#pragma unroll
        for (int t = 0; t < 2; ++t) {
            const int ks = c * 2 + t;
            short8 afr[4], bfr[4];
#pragma unroll
            for (int fm = 0; fm < 4; ++fm)
                afr[fm] = *reinterpret_cast<const short8*>(&As2[buf][fm * 16 + l16][t * 32 + g * 8]);
#pragma unroll
            for (int fn = 0; fn < 4; ++fn)
                bfr[fn] = Bv[((ks * 4 + wid) * 4 + fn) * 64 + lane];
#pragma unroll
            for (int fm = 0; fm < 4; ++fm)
#pragma unroll
                for (int fn = 0; fn < 4; ++fn)
                    acc[fm][fn] = __builtin_amdgcn_mfma_f32_16x16x32_bf16(
                        afr[fm], bfr[fn], acc[fm][fn], 0, 0, 0);
        }
        if (c < 15) {
#pragma unroll
            for (int p = 0; p < 4; ++p) {
                ushort4 u;
                u.x = f2bf(rcur[p].x); u.y = f2bf(rcur[p].y);
                u.z = f2bf(rcur[p].z); u.w = f2bf(rcur[p].w);
                *reinterpret_cast<ushort4*>(&As2[buf ^ 1][p * 16 + srow][scol]) = u;
            }
        }
        __syncthreads();
#pragma unroll
        for (int p = 0; p < 4; ++p) rcur[p] = rnext[p];
    }

#pragma unroll
    for (int fm = 0; fm < 4; ++fm) {
#pragma unroll
        for (int r = 0; r < 4; ++r) {
            int row = m0 + fm * 16 + g * 4 + r;
            if (row < M) {
#pragma unroll
                for (int fn = 0; fn < 4; ++fn)
                    P[(size_t)row * 256 + colbase + fn * 16] = f2bf(acc[fm][fn][r]);
            }
        }
    }
}

// ---------- MLP head via MFMA (z bf16 + addf direct) ----------
__global__ __launch_bounds__(256) void mlp_mfma(
    const unsigned short* __restrict__ z, const float* __restrict__ addf,
    const unsigned short* __restrict__ Bt1p,
    const float* __restrict__ fc1b, const float* __restrict__ bnfg, const float* __restrict__ bnfb,
    const float* __restrict__ fc2W, const float* __restrict__ fc2b,
    float* __restrict__ out, int M)
{
    __shared__ __align__(16) char smem[64 * 169 * 4];
    unsigned short (*zs)[200] = reinterpret_cast<unsigned short(*)[200]>(smem);
    float (*ts)[169] = reinterpret_cast<float(*)[169]>(smem);
    const int tid = threadIdx.x;
    const int wid = tid >> 6, lane = tid & 63;
    const int m0 = blockIdx.x * 64;
    const int l16 = lane & 15, g = lane >> 4;
    const short8* Bv = reinterpret_cast<const short8*>(Bt1p);

#pragma unroll
    for (int p = 0; p < 13; ++p) {
        int idx = p * 256 + tid;
        if (idx < 3200) {
            int row = idx / 50, c4 = (idx % 50) * 4;
            int ar = m0 + row;
            ushort4 u; u.x = 0; u.y = 0; u.z = 0; u.w = 0;
            if (ar < M) {
                if (c4 < 148) {
                    u = *reinterpret_cast<const ushort4*>(&z[(size_t)ar * 168 + c4]);
                } else if (c4 < 168) {
                    float4 v = *reinterpret_cast<const float4*>(&addf[(size_t)ar * 20 + (c4 - 148)]);
                    u.x = f2bf(v.x); u.y = f2bf(v.y); u.z = f2bf(v.z); u.w = f2bf(v.w);
                }
            }
            *reinterpret_cast<ushort4*>(&zs[row][c4]) = u;
        }
    }
    __syncthreads();

    f32x4 acc[4][4] = {};
    if (wid < 3) {
#pragma unroll
        for (int t = 0; t < 6; ++t) {
            short8 afr[4], bfr[4];
#pragma unroll
            for (int fm = 0; fm < 4; ++fm)
                afr[fm] = *reinterpret_cast<const short8*>(&zs[fm * 16 + l16][t * 32 + g * 8]);
#pragma unroll
            for (int fn = 0; fn < 4; ++fn)
                bfr[fn] = Bv[((t * 3 + wid) * 4 + fn) * 64 + lane];
#pragma unroll
            for (int fm = 0; fm < 4; ++fm)
#pragma unroll
                for (int fn = 0; fn < 4; ++fn)
                    acc[fm][fn] = __builtin_amdgcn_mfma_f32_16x16x32_bf16(
                        afr[fm], bfr[fn], acc[fm][fn], 0, 0, 0);
        }
    }
    __syncthreads();
    if (wid < 3) {
        const int colbase = wid * 64 + l16;
#pragma unroll
        for (int fm = 0; fm < 4; ++fm) {
#pragma unroll
            for (int r = 0; r < 4; ++r) {
                int rr = fm * 16 + g * 4 + r;
#pragma unroll
                for (int fn = 0; fn < 4; ++fn) {
                    int col = colbase + fn * 16;
                    if (col < 168) {
                        float v = acc[fm][fn][r] + fc1b[col];
                        v = v * (bnfg[col] * BN_RSQ) + bnfb[col];
                        ts[rr][col] = fmaxf(v, 0.0f);
                    }
                }
            }
        }
    }
    __syncthreads();
    if (tid < 192) {
        int r = tid & 63, c = tid >> 6;
        float acc2 = fc2b[c];
#pragma unroll 4
        for (int k = 0; k < 168; ++k) acc2 += ts[r][k] * fc2W[k * 3 + c];
        int row = m0 + r;
        if (row < M) out[(size_t)row * 3 + c] = acc2;
    }
}

// ---------- histograms + edge attrs ----------
__global__ void edge_count(const int* __restrict__ e1d, const int* __restrict__ e2d,
                           const float* __restrict__ ef,
                           int* __restrict__ cnt1, int* __restrict__ cnt2,
                           float* __restrict__ easum, float* __restrict__ eaext, int E)
{
    int e = blockIdx.x * blockDim.x + threadIdx.x;
    if (e >= E) return;
    atomicAdd(&cnt1[e1d[e]], 1);
    int d2 = e2d[e];
    atomicAdd(&cnt2[d2], 1);
    float a = ef[e];
    atomicAdd(&easum[d2], a);
    eaext[e] = a;
}

// ---------- exclusive scans (y-fused for both CSRs) ----------
__global__ void scan1(const int* __restrict__ cnt1, const int* __restrict__ cnt2,
                      int* __restrict__ off1, int* __restrict__ off2,
                      int* __restrict__ bsum1, int* __restrict__ bsum2, int M)
{
    __shared__ int sh[SCAN_B];
    int y = blockIdx.y;
    const int* cnt = y ? cnt2 : cnt1;
    int* excl = y ? off2 : off1;
    int* bsum = y ? bsum2 : bsum1;
    int i = blockIdx.x * SCAN_B + threadIdx.x;
    int v = (i < M) ? cnt[i] + y : 0;
    sh[threadIdx.x] = v;
    __syncthreads();
    for (int o = 1; o < SCAN_B; o <<= 1) {
        int t = (threadIdx.x >= o) ? sh[threadIdx.x - o] : 0;
        __syncthreads();
        sh[threadIdx.x] += t;
        __syncthreads();
    }
    if (i < M) excl[i] = sh[threadIdx.x] - v;
    if (threadIdx.x == SCAN_B - 1) bsum[blockIdx.x] = sh[threadIdx.x];
}

__global__ void scan2(int* __restrict__ bsum1, int* __restrict__ bsum2, int nb)
{
    __shared__ int sh[SCAN_B];
    int* bsum = blockIdx.y ? bsum2 : bsum1;
    int v = ((int)threadIdx.x < nb) ? bsum[threadIdx.x] : 0;
    sh[threadIdx.x] = v;
    __syncthreads();
    for (int o = 1; o < SCAN_B; o <<= 1) {
        int t = (threadIdx.x >= o) ? sh[threadIdx.x - o] : 0;
        __syncthreads();
        sh[threadIdx.x] += t;
        __syncthreads();
    }
    if ((int)threadIdx.x < nb) bsum[threadIdx.x] = sh[threadIdx.x] - v;
}

__global__ void scan3(int* __restrict__ off1, int* __restrict__ off2,
                      const int* __restrict__ bsum1, const int* __restrict__ bsum2,
                      const int* __restrict__ cnt1, const int* __restrict__ cnt2,
                      const float* __restrict__ easum, float* __restrict__ eaext,
                      int E, int M)
{
    int y = blockIdx.y;
    int* off = y ? off2 : off1;
    const int* bsum = y ? bsum2 : bsum1;
    const int* cnt = y ? cnt2 : cnt1;
    int i = blockIdx.x * SCAN_B + threadIdx.x;
    if (i < M) {
        int v = off[i] + bsum[blockIdx.x];
        off[i] = v;
        if (i == M - 1) off[M] = v + cnt[i] + y;   // sentinel (add1 == y)
        if (y) eaext[E + i] = easum[i] / fmaxf((float)cnt2[i], 1.0f);
    }
}

// ---------- fused CSR fill (both graphs; cnt used as down-counting cursor) ----------
__global__ void fill_both(const int* __restrict__ e1s, const int* __restrict__ e1d,
                          const int* __restrict__ e2d,
                          const int* __restrict__ off1, const int* __restrict__ off2,
                          int* __restrict__ cnt1, int* __restrict__ cnt2,
                          int* __restrict__ srcs1, int* __restrict__ eidx2, int E, int Eext)
{
    int t = blockIdx.x * blockDim.x + threadIdx.x;
    if (t < E) {
        int d = e1d[t];
        int pos = atomicSub(&cnt1[d], 1) - 1;
        srcs1[off1[d] + pos] = e1s[t];
    }
    int t2 = t - E;
    if (t2 >= 0 && t2 < Eext) {
        if (t2 < E) {
            int d = e2d[t2];
            int pos = atomicSub(&cnt2[d], 1) - 1;
            eidx2[off2[d] + pos] = t2;
        } else {
            int nn = t2 - E;
            eidx2[off2[nn + 1] - 1] = t2;   // self-loop takes the last slot
        }
    }
}

// ---------- SAGE gather (bf16 P), fused BN/act epilogue into bf16 z ----------
__global__ void sage_gather(const int* __restrict__ srcs1, const int* __restrict__ off1,
                            const unsigned short* __restrict__ P, const float* __restrict__ bl,
                            const float* __restrict__ bng, const float* __restrict__ bnb,
                            unsigned short* __restrict__ z, int N)
{
    int t = blockIdx.x * blockDim.x + threadIdx.x;
    if (t >= N * 32) return;
    int n = t >> 5, g = t & 31;
    int beg = off1[n], end = off1[n + 1];
    float a0 = 0.f, a1 = 0.f, a2 = 0.f, a3 = 0.f;
    for (int j = beg; j < end; ++j) {
        int s = srcs1[j];
        ushort4 v = *reinterpret_cast<const ushort4*>(&P[(size_t)s * 256 + g * 4]);
        a0 += bf2f(v.x); a1 += bf2f(v.y); a2 += bf2f(v.z); a3 += bf2f(v.w);
    }
    float inv = 1.0f / fmaxf((float)(end - beg), 1.0f);
    ushort4 pr = *reinterpret_cast<const ushort4*>(&P[(size_t)n * 256 + 128 + g * 4]);
    float a4[4] = {a0, a1, a2, a3};
    float p4[4] = {bf2f(pr.x), bf2f(pr.y), bf2f(pr.z), bf2f(pr.w)};
    ushort4 zo;
    unsigned short* zp = reinterpret_cast<unsigned short*>(&zo);
#pragma unroll
    for (int k = 0; k < 4; ++k) {
        int cc = g * 4 + k;
        float x = a4[k] * inv + bl[cc] + p4[k];
        x = x * (bng[cc] * BN_RSQ) + bnb[cc];
        zp[k] = f2bf(lrelu(x, 0.01f));
    }
    *reinterpret_cast<ushort4*>(&z[(size_t)n * 168 + g * 4]) = zo;
}

// ---------- GATv2 linear projections ----------
template <int IND, int HC>
__global__ void gat_lin(const float* __restrict__ X,
                        const float* __restrict__ Wl, const float* __restrict__ bl,
                        const float* __restrict__ Wr, const float* __restrict__ br,
                        float* __restrict__ xl, float* __restrict__ xr, int N)
{
    int t = blockIdx.x * blockDim.x + threadIdx.x;
    if (t >= N * HC) return;
    int n = t / HC, j = t % HC;
    float al = bl[j], ar = br[j];
    const float* xrow = X + (size_t)n * IND;
#pragma unroll 4
    for (int k = 0; k < IND; ++k) {
        float xv = xrow[k];
        al += xv * Wl[k * HC + j];
        ar += xv * Wr[k * HC + j];
    }
    xl[t] = al;
    xr[t] = ar;
}

// ---------- fused GATv2 per (node, head): ONE pass, online softmax ----------
// MODE 1: out fp32 y = lrelu(out+b)  | MODE 2: out bf16 z[.,128..148) = lrelu(bn(out+b))
template <int H, int C, int MODE>
__global__ void gat_node(const int* __restrict__ eidx2, const int* __restrict__ off2,
                         const int* __restrict__ e2s, const float* __restrict__ eaext,
                         const float* __restrict__ xl, const float* __restrict__ xr,
                         const float* __restrict__ We, const float* __restrict__ att,
                         const float* __restrict__ b,
                         const float* __restrict__ bng, const float* __restrict__ bnb,
                         void* __restrict__ outv, int E, int N)
{
    int t = blockIdx.x * blockDim.x + threadIdx.x;
    if (t >= N * H) return;
    int n = t / H, h = t % H;

    float xrc[C], atth[C], weh[C];
#pragma unroll
    for (int c = 0; c < C; ++c) {
        xrc[c]  = xr[(size_t)n * (H * C) + h * C + c];
        atth[c] = att[h * C + c];
        weh[c]  = We[h * C + c];
    }

    const int beg = off2[n], end = off2[n + 1];

    float mx = -FLT_MAX, den = 0.0f;
    float accv[C] = {};
    for (int j = beg; j < end; ++j) {
        int e = eidx2[j];
        int s = (e < E) ? e2s[e] : (e - E);
        float ea = eaext[e];
        const float* xls = xl + (size_t)s * (H * C) + h * C;
        float xv[C];
        float lg = 0.0f;
#pragma unroll
        for (int c = 0; c < C; ++c) {
            xv[c] = xls[c];
            float m = xv[c] + xrc[c] + ea * weh[c];
            lg += lrelu(m, 0.2f) * atth[c];
        }
        if (lg > mx) {
            float sc = __expf(mx - lg);   // first iter: exp(-inf)=0, den/accv are 0 anyway
            den *= sc;
#pragma unroll
            for (int c = 0; c < C; ++c) accv[c] *= sc;
            mx = lg;
        }
        float ex = __expf(lg - mx);
        den += ex;
#pragma unroll
        for (int c = 0; c < C; ++c) accv[c] += ex * xv[c];
    }
    float inv = 1.0f / (den + 1e-16f);

#pragma unroll
    for (int c = 0; c < C; ++c) {
        int jch = h * C + c;
        float v = accv[c] * inv + b[jch];
        if (MODE == 1) {
            ((float*)outv)[(size_t)n * (H * C) + jch] = lrelu(v, 0.01f);
        } else {
            v = v * (bng[jch] * BN_RSQ) + bnb[jch];
            ((unsigned short*)outv)[(size_t)n * 168 + 128 + jch] = f2bf(lrelu(v, 0.01f));
        }
    }
}

// ---------- launch ----------
extern "C" void kernel_launch(void* const* d_in, const int* in_sizes, int n_in,
                              void* d_out, int out_size, void* d_ws, size_t ws_size,
                              hipStream_t stream)
{
    const float* features = (const float*)d_in[0];
    const int*   e1       = (const int*)d_in[1];
    const int*   e2       = (const int*)d_in[2];
    const float* ef       = (const float*)d_in[3];
    const float* addf     = (const float*)d_in[4];
    const float* sage_Wl  = (const float*)d_in[5];
    const float* sage_bl  = (const float*)d_in[6];
    const float* sage_Wr  = (const float*)d_in[7];
    const float* g1_Wl = (const float*)d_in[8];
    const float* g1_bl = (const float*)d_in[9];
    const float* g1_Wr = (const float*)d_in[10];
    const float* g1_br = (const float*)d_in[11];
    const float* g1_We = (const float*)d_in[12];
    const float* g1_att = (const float*)d_in[13];
    const float* g1_b = (const float*)d_in[14];
    const float* g2_Wl = (const float*)d_in[15];
    const float* g2_bl = (const float*)d_in[16];
    const float* g2_Wr = (const float*)d_in[17];
    const float* g2_br = (const float*)d_in[18];
    const float* g2_We = (const float*)d_in[19];
    const float* g2_att = (const float*)d_in[20];
    const float* g2_b = (const float*)d_in[21];
    const float* fc1_W = (const float*)d_in[22];
    const float* fc1_b = (const float*)d_in[23];
    const float* fc2_W = (const float*)d_in[24];
    const float* fc2_b = (const float*)d_in[25];
    const float* bnx_g = (const float*)d_in[26];
    const float* bnx_b = (const float*)d_in[27];
    const float* bny_g = (const float*)d_in[28];
    const float* bny_b = (const float*)d_in[29];
    const float* bnf_g = (const float*)d_in[30];
    const float* bnf_b = (const float*)d_in[31];

    const int N = in_sizes[0] / 1024;
    const int E = in_sizes[3];
    const int Eext = E + N;
    const int* e1s = e1, *e1d = e1 + E;
    const int* e2s = e2, *e2d = e2 + E;
    const int nb = (N + SCAN_B - 1) / SCAN_B;

    char* wb = (char*)d_ws;
    size_t off = 0;
    auto takeB = [&](size_t bytes) { char* p = wb + off; off = (off + bytes + 255) & ~(size_t)255; return p; };
    unsigned short* P = (unsigned short*)takeB((size_t)N * 256 * 2);
    unsigned short* z = (unsigned short*)takeB((size_t)N * 168 * 2);
    float* eaext = (float*)takeB((size_t)Eext * 4);
    float* xl1   = (float*)takeB((size_t)N * 40 * 4);
    float* xr1   = (float*)takeB((size_t)N * 40 * 4);
    float* y1    = (float*)takeB((size_t)N * 40 * 4);
    float* xl2   = (float*)takeB((size_t)N * 20 * 4);
    float* xr2   = (float*)takeB((size_t)N * 20 * 4);
    unsigned short* Btp  = (unsigned short*)takeB((size_t)256 * 1024 * 2);
    unsigned short* Bt1p = (unsigned short*)takeB((size_t)36864 * 2);
    // zero-init region: cnt1, cnt2, easum contiguous
    char* zero_beg = wb + off;
    int* cnt1    = (int*)takeB((size_t)N * 4);
    int* cnt2    = (int*)takeB((size_t)N * 4);
    float* easum = (float*)takeB((size_t)N * 4);
    size_t zero_len = (size_t)((wb + off) - zero_beg);
    int* off1  = (int*)takeB((size_t)(N + 1) * 4);
    int* off2  = (int*)takeB((size_t)(N + 1) * 4);
    int* bsum1 = (int*)takeB(SCAN_B * 4);
    int* bsum2 = (int*)takeB(SCAN_B * 4);
    int* srcs1 = (int*)takeB((size_t)E * 4);
    int* eidx2 = (int*)takeB((size_t)Eext * 4);

    hipMemsetAsync(zero_beg, 0, zero_len, stream);

    const int B = 256;
    conv_wsage<<<(256 * 1024 + B - 1) / B, B, 0, stream>>>(sage_Wl, sage_Wr, Btp);
    conv_wfc1<<<(36864 + B - 1) / B, B, 0, stream>>>(fc1_W, Bt1p);

    edge_count<<<(E + B - 1) / B, B, 0, stream>>>(e1d, e2d, ef, cnt1, cnt2, easum, eaext, E);

    scan1<<<dim3(nb, 2), SCAN_B, 0, stream>>>(cnt1, cnt2, off1, off2, bsum1, bsum2, N);
    scan2<<<dim3(1, 2), SCAN_B, 0, stream>>>(bsum1, bsum2, nb);
    scan3<<<dim3(nb, 2), SCAN_B, 0, stream>>>(off1, off2, bsum1, bsum2, cnt1, cnt2,
                                              easum, eaext, E, N);

    fill_both<<<(E + Eext + B - 1) / B, B, 0, stream>>>(e1s, e1d, e2d, off1, off2,
                                                        cnt1, cnt2, srcs1, eidx2, E, Eext);

    const int mtiles = (N + 63) / 64;
    gemm_sage_mfma<<<mtiles, 256, 0, stream>>>(features, Btp, P, N);
    sage_gather<<<(N * 32 + B - 1) / B, B, 0, stream>>>(srcs1, off1, P, sage_bl, bnx_g, bnx_b, z, N);

    gat_lin<20, 40><<<(N * 40 + B - 1) / B, B, 0, stream>>>(addf, g1_Wl, g1_bl, g1_Wr, g1_br, xl1, xr1, N);
    gat_node<4, 10, 1><<<(N * 4 + B - 1) / B, B, 0, stream>>>(
        eidx2, off2, e2s, eaext, xl1, xr1, g1_We, g1_att, g1_b,
        nullptr, nullptr, (void*)y1, E, N);

    gat_lin<40, 20><<<(N * 20 + B - 1) / B, B, 0, stream>>>(y1, g2_Wl, g2_bl, g2_Wr, g2_br, xl2, xr2, N);
    gat_node<4, 5, 2><<<(N * 4 + B - 1) / B, B, 0, stream>>>(
        eidx2, off2, e2s, eaext, xl2, xr2, g2_We, g2_att, g2_b,
        bny_g, bny_b, (void*)z, E, N);

    mlp_mfma<<<mtiles, 256, 0, stream>>>(z, addf, Bt1p, fc1_b, bnf_g, bnf_b, fc2_W, fc2_b,
                                         (float*)d_out, N);
}

// Round 6
// 307.500 us; speedup vs baseline: 7.7575x; 1.0378x over previous
//
#include <hip/hip_runtime.h>
#include <hip/hip_bf16.h>
#include <cfloat>

__device__ __forceinline__ float lrelu(float x, float a) { return x > 0.0f ? x : a * x; }

// fp32 -> bf16 round-to-nearest-even (bit pattern)
__device__ __forceinline__ unsigned short f2bf(float f) {
    unsigned u = __float_as_uint(f);
    unsigned r = (u + 0x7FFFu + ((u >> 16) & 1u)) >> 16;
    return (unsigned short)r;
}
__device__ __forceinline__ float bf2f(unsigned short u) {
    return __uint_as_float((unsigned)u << 16);
}

typedef __attribute__((ext_vector_type(8))) short short8;
typedef __attribute__((ext_vector_type(4))) float f32x4;

#define BN_RSQ 0.99999500003749968750f  // 1/sqrt(1+1e-5)
#define SCAN_B 256

// ---------- fast zero (replaces pathological hipMemsetAsync fillBuffer) ----------
__global__ void zero_ws(uint4* __restrict__ p, int n16)
{
    int t = blockIdx.x * blockDim.x + threadIdx.x;
    if (t < n16) p[t] = make_uint4(0u, 0u, 0u, 0u);
}

// ---------- weight conversion into MFMA fragment-order (coalesced) layouts ----------
__global__ void conv_wsage(const float* __restrict__ Wl, const float* __restrict__ Wr,
                           unsigned short* __restrict__ Btp)
{
    int idx = blockIdx.x * blockDim.x + threadIdx.x;
    if (idx >= 256 * 1024) return;
    int j    = idx & 7;
    int lane = (idx >> 3) & 63;
    int fn   = (idx >> 9) & 3;
    int wid  = (idx >> 11) & 3;
    int t    = idx >> 13;                    // kstep 0..31
    int c = wid * 64 + fn * 16 + (lane & 15);
    int k = t * 32 + (lane >> 4) * 8 + j;
    float v = (c < 128) ? Wl[(size_t)k * 128 + c] : Wr[(size_t)k * 128 + (c - 128)];
    Btp[idx] = f2bf(v);
}

__global__ void conv_wfc1(const float* __restrict__ fc1W, unsigned short* __restrict__ Bt1p)
{
    int idx = blockIdx.x * blockDim.x + threadIdx.x;
    if (idx >= 36864) return;
    int j    = idx & 7;
    int lane = (idx >> 3) & 63;
    int fn   = (idx >> 9) & 3;
    int q    = idx >> 11;                    // t*3 + wid, 0..17
    int wid = q % 3, t = q / 3;
    int c = wid * 64 + fn * 16 + (lane & 15);
    int k = t * 32 + (lane >> 4) * 8 + j;
    float v = (c < 168 && k < 168) ? fc1W[(size_t)k * 168 + c] : 0.0f;
    Bt1p[idx] = f2bf(v);
}

// ---------- SAGE GEMM via MFMA, 2-deep A prefetch; B issued BEFORE A so MFMA's
// vmcnt wait leaves the A-prefetch in flight (counted-vmcnt semantics) ----------
__global__ __launch_bounds__(256) void gemm_sage_mfma(
    const float* __restrict__ A, const unsigned short* __restrict__ Btp,
    unsigned short* __restrict__ P, int M)
{
    __shared__ unsigned short As2[2][64][72];
    const int tid = threadIdx.x;
    const int wid = tid >> 6, lane = tid & 63;
    const int m0 = blockIdx.x * 64;
    const int l16 = lane & 15, g = lane >> 4;
    const int colbase = wid * 64 + l16;
    const short8* Bv = reinterpret_cast<const short8*>(Btp);
    const int srow = tid >> 4, scol = (tid & 15) * 4;

    f32x4 acc[4][4] = {};
    float4 rcur[4], rnext[4];

    // prolog: chunk0 -> LDS0; chunk1 -> rcur
#pragma unroll
    for (int p = 0; p < 4; ++p) {
        int ar = m0 + p * 16 + srow;
        rcur[p] = make_float4(0.f, 0.f, 0.f, 0.f);
        if (ar < M) rcur[p] = *reinterpret_cast<const float4*>(&A[(size_t)ar * 1024 + scol]);
    }
#pragma unroll
    for (int p = 0; p < 4; ++p) {
        ushort4 u;
        u.x = f2bf(rcur[p].x); u.y = f2bf(rcur[p].y); u.z = f2bf(rcur[p].z); u.w = f2bf(rcur[p].w);
        *reinterpret_cast<ushort4*>(&As2[0][p * 16 + srow][scol]) = u;
    }
#pragma unroll
    for (int p = 0; p < 4; ++p) {
        int ar = m0 + p * 16 + srow;
        rcur[p] = make_float4(0.f, 0.f, 0.f, 0.f);
        if (ar < M) rcur[p] = *reinterpret_cast<const float4*>(&A[(size_t)ar * 1024 + 64 + scol]);
    }
    __syncthreads();

    for (int c = 0; c < 16; ++c) {
        const int buf = c & 1;
        // 1) B fragments for this chunk (L2-resident), issued FIRST
        short8 bfr[2][4];
#pragma unroll
        for (int t = 0; t < 2; ++t)
#pragma unroll
            for (int fn = 0; fn < 4; ++fn)
                bfr[t][fn] = Bv[(((c * 2 + t) * 4 + wid) * 4 + fn) * 64 + lane];
        __builtin_amdgcn_sched_barrier(0);
        // 2) A prefetch for chunk c+2 (stays in flight across the MFMA phase)
        if (c < 14) {
            const int k0 = (c + 2) * 64;
#pragma unroll
            for (int p = 0; p < 4; ++p) {
                int ar = m0 + p * 16 + srow;
                rnext[p] = make_float4(0.f, 0.f, 0.f, 0.f);
                if (ar < M) rnext[p] = *reinterpret_cast<const float4*>(&A[(size_t)ar * 1024 + k0 + scol]);
            }
        }
        __builtin_amdgcn_sched_barrier(0);
        // 3) compute (waits B via vmcnt(4); A-prefetch keeps flying)
#pragma unroll
        for (int t = 0; t < 2; ++t) {
            short8 afr[4];
#pragma unroll
            for (int fm = 0; fm < 4; ++fm)
                afr[fm] = *reinterpret_cast<const short8*>(&As2[buf][fm * 16 + l16][t * 32 + g * 8]);
#pragma unroll
            for (int fm = 0; fm < 4; ++fm)
#pragma unroll
                for (int fn = 0; fn < 4; ++fn)
                    acc[fm][fn] = __builtin_amdgcn_mfma_f32_16x16x32_bf16(
                        afr[fm], bfr[t][fn], acc[fm][fn], 0, 0, 0);
        }
        // 4) stage chunk c+1 (rcur, loaded 1 iter ago) into the other LDS buffer
        if (c < 15) {
#pragma unroll
            for (int p = 0; p < 4; ++p) {
                ushort4 u;
                u.x = f2bf(rcur[p].x); u.y = f2bf(rcur[p].y);
                u.z = f2bf(rcur[p].z); u.w = f2bf(rcur[p].w);
                *reinterpret_cast<ushort4*>(&As2[buf ^ 1][p * 16 + srow][scol]) = u;
            }
        }
        __syncthreads();
#pragma unroll
        for (int p = 0; p < 4; ++p) rcur[p] = rnext[p];
    }

#pragma unroll
    for (int fm = 0; fm < 4; ++fm) {
#pragma unroll
        for (int r = 0; r < 4; ++r) {
            int row = m0 + fm * 16 + g * 4 + r;
            if (row < M) {
#pragma unroll
                for (int fn = 0; fn < 4; ++fn)
                    P[(size_t)row * 256 + colbase + fn * 16] = f2bf(acc[fm][fn][r]);
            }
        }
    }
}

// ---------- MLP head via MFMA (z bf16 + addf direct) ----------
__global__ __launch_bounds__(256) void mlp_mfma(
    const unsigned short* __restrict__ z, const float* __restrict__ addf,
    const unsigned short* __restrict__ Bt1p,
    const float* __restrict__ fc1b, const float* __restrict__ bnfg, const float* __restrict__ bnfb,
    const float* __restrict__ fc2W, const float* __restrict__ fc2b,
    float* __restrict__ out, int M)
{
    __shared__ __align__(16) char smem[64 * 169 * 4];
    unsigned short (*zs)[200] = reinterpret_cast<unsigned short(*)[200]>(smem);
    float (*ts)[169] = reinterpret_cast<float(*)[169]>(smem);
    const int tid = threadIdx.x;
    const int wid = tid >> 6, lane = tid & 63;
    const int m0 = blockIdx.x * 64;
    const int l16 = lane & 15, g = lane >> 4;
    const short8* Bv = reinterpret_cast<const short8*>(Bt1p);

#pragma unroll
    for (int p = 0; p < 13; ++p) {
        int idx = p * 256 + tid;
        if (idx < 3200) {
            int row = idx / 50, c4 = (idx % 50) * 4;
            int ar = m0 + row;
            ushort4 u; u.x = 0; u.y = 0; u.z = 0; u.w = 0;
            if (ar < M) {
                if (c4 < 148) {
                    u = *reinterpret_cast<const ushort4*>(&z[(size_t)ar * 168 + c4]);
                } else if (c4 < 168) {
                    float4 v = *reinterpret_cast<const float4*>(&addf[(size_t)ar * 20 + (c4 - 148)]);
                    u.x = f2bf(v.x); u.y = f2bf(v.y); u.z = f2bf(v.z); u.w = f2bf(v.w);
                }
            }
            *reinterpret_cast<ushort4*>(&zs[row][c4]) = u;
        }
    }
    __syncthreads();

    f32x4 acc[4][4] = {};
    if (wid < 3) {
#pragma unroll
        for (int t = 0; t < 6; ++t) {
            short8 afr[4], bfr[4];
#pragma unroll
            for (int fm = 0; fm < 4; ++fm)
                afr[fm] = *reinterpret_cast<const short8*>(&zs[fm * 16 + l16][t * 32 + g * 8]);
#pragma unroll
            for (int fn = 0; fn < 4; ++fn)
                bfr[fn] = Bv[((t * 3 + wid) * 4 + fn) * 64 + lane];
#pragma unroll
            for (int fm = 0; fm < 4; ++fm)
#pragma unroll
                for (int fn = 0; fn < 4; ++fn)
                    acc[fm][fn] = __builtin_amdgcn_mfma_f32_16x16x32_bf16(
                        afr[fm], bfr[fn], acc[fm][fn], 0, 0, 0);
        }
    }
    __syncthreads();
    if (wid < 3) {
        const int colbase = wid * 64 + l16;
#pragma unroll
        for (int fm = 0; fm < 4; ++fm) {
#pragma unroll
            for (int r = 0; r < 4; ++r) {
                int rr = fm * 16 + g * 4 + r;
#pragma unroll
                for (int fn = 0; fn < 4; ++fn) {
                    int col = colbase + fn * 16;
                    if (col < 168) {
                        float v = acc[fm][fn][r] + fc1b[col];
                        v = v * (bnfg[col] * BN_RSQ) + bnfb[col];
                        ts[rr][col] = fmaxf(v, 0.0f);
                    }
                }
            }
        }
    }
    __syncthreads();
    if (tid < 192) {
        int r = tid & 63, c = tid >> 6;
        float acc2 = fc2b[c];
#pragma unroll 4
        for (int k = 0; k < 168; ++k) acc2 += ts[r][k] * fc2W[k * 3 + c];
        int row = m0 + r;
        if (row < M) out[(size_t)row * 3 + c] = acc2;
    }
}

// ---------- histograms + edge attrs ----------
__global__ void edge_count(const int* __restrict__ e1d, const int* __restrict__ e2d,
                           const float* __restrict__ ef,
                           int* __restrict__ cnt1, int* __restrict__ cnt2,
                           float* __restrict__ easum, float* __restrict__ eaext, int E)
{
    int e = blockIdx.x * blockDim.x + threadIdx.x;
    if (e >= E) return;
    atomicAdd(&cnt1[e1d[e]], 1);
    int d2 = e2d[e];
    atomicAdd(&cnt2[d2], 1);
    float a = ef[e];
    atomicAdd(&easum[d2], a);
    eaext[e] = a;
}

// ---------- exclusive scans (y-fused for both CSRs) ----------
__global__ void scan1(const int* __restrict__ cnt1, const int* __restrict__ cnt2,
                      int* __restrict__ off1, int* __restrict__ off2,
                      int* __restrict__ bsum1, int* __restrict__ bsum2, int M)
{
    __shared__ int sh[SCAN_B];
    int y = blockIdx.y;
    const int* cnt = y ? cnt2 : cnt1;
    int* excl = y ? off2 : off1;
    int* bsum = y ? bsum2 : bsum1;
    int i = blockIdx.x * SCAN_B + threadIdx.x;
    int v = (i < M) ? cnt[i] + y : 0;
    sh[threadIdx.x] = v;
    __syncthreads();
    for (int o = 1; o < SCAN_B; o <<= 1) {
        int t = (threadIdx.x >= o) ? sh[threadIdx.x - o] : 0;
        __syncthreads();
        sh[threadIdx.x] += t;
        __syncthreads();
    }
    if (i < M) excl[i] = sh[threadIdx.x] - v;
    if (threadIdx.x == SCAN_B - 1) bsum[blockIdx.x] = sh[threadIdx.x];
}

__global__ void scan2(int* __restrict__ bsum1, int* __restrict__ bsum2, int nb)
{
    __shared__ int sh[SCAN_B];
    int* bsum = blockIdx.y ? bsum2 : bsum1;
    int v = ((int)threadIdx.x < nb) ? bsum[threadIdx.x] : 0;
    sh[threadIdx.x] = v;
    __syncthreads();
    for (int o = 1; o < SCAN_B; o <<= 1) {
        int t = (threadIdx.x >= o) ? sh[threadIdx.x - o] : 0;
        __syncthreads();
        sh[threadIdx.x] += t;
        __syncthreads();
    }
    if ((int)threadIdx.x < nb) bsum[threadIdx.x] = sh[threadIdx.x] - v;
}

__global__ void scan3(int* __restrict__ off1, int* __restrict__ off2,
                      const int* __restrict__ bsum1, const int* __restrict__ bsum2,
                      const int* __restrict__ cnt1, const int* __restrict__ cnt2,
                      const float* __restrict__ easum, float* __restrict__ eaext,
                      int E, int M)
{
    int y = blockIdx.y;
    int* off = y ? off2 : off1;
    const int* bsum = y ? bsum2 : bsum1;
    const int* cnt = y ? cnt2 : cnt1;
    int i = blockIdx.x * SCAN_B + threadIdx.x;
    if (i < M) {
        int v = off[i] + bsum[blockIdx.x];
        off[i] = v;
        if (i == M - 1) off[M] = v + cnt[i] + y;   // sentinel (add1 == y)
        if (y) eaext[E + i] = easum[i] / fmaxf((float)cnt2[i], 1.0f);
    }
}

// ---------- fused CSR fill (both graphs; cnt used as down-counting cursor) ----------
__global__ void fill_both(const int* __restrict__ e1s, const int* __restrict__ e1d,
                          const int* __restrict__ e2d,
                          const int* __restrict__ off1, const int* __restrict__ off2,
                          int* __restrict__ cnt1, int* __restrict__ cnt2,
                          int* __restrict__ srcs1, int* __restrict__ eidx2, int E, int Eext)
{
    int t = blockIdx.x * blockDim.x + threadIdx.x;
    if (t < E) {
        int d = e1d[t];
        int pos = atomicSub(&cnt1[d], 1) - 1;
        srcs1[off1[d] + pos] = e1s[t];
    }
    int t2 = t - E;
    if (t2 >= 0 && t2 < Eext) {
        if (t2 < E) {
            int d = e2d[t2];
            int pos = atomicSub(&cnt2[d], 1) - 1;
            eidx2[off2[d] + pos] = t2;
        } else {
            int nn = t2 - E;
            eidx2[off2[nn + 1] - 1] = t2;   // self-loop takes the last slot
        }
    }
}

// ---------- SAGE gather (bf16 P), fused BN/act epilogue into bf16 z ----------
__global__ void sage_gather(const int* __restrict__ srcs1, const int* __restrict__ off1,
                            const unsigned short* __restrict__ P, const float* __restrict__ bl,
                            const float* __restrict__ bng, const float* __restrict__ bnb,
                            unsigned short* __restrict__ z, int N)
{
    int t = blockIdx.x * blockDim.x + threadIdx.x;
    if (t >= N * 32) return;
    int n = t >> 5, g = t & 31;
    int beg = off1[n], end = off1[n + 1];
    float a0 = 0.f, a1 = 0.f, a2 = 0.f, a3 = 0.f;
    for (int j = beg; j < end; ++j) {
        int s = srcs1[j];
        ushort4 v = *reinterpret_cast<const ushort4*>(&P[(size_t)s * 256 + g * 4]);
        a0 += bf2f(v.x); a1 += bf2f(v.y); a2 += bf2f(v.z); a3 += bf2f(v.w);
    }
    float inv = 1.0f / fmaxf((float)(end - beg), 1.0f);
    ushort4 pr = *reinterpret_cast<const ushort4*>(&P[(size_t)n * 256 + 128 + g * 4]);
    float a4[4] = {a0, a1, a2, a3};
    float p4[4] = {bf2f(pr.x), bf2f(pr.y), bf2f(pr.z), bf2f(pr.w)};
    ushort4 zo;
    unsigned short* zp = reinterpret_cast<unsigned short*>(&zo);
#pragma unroll
    for (int k = 0; k < 4; ++k) {
        int cc = g * 4 + k;
        float x = a4[k] * inv + bl[cc] + p4[k];
        x = x * (bng[cc] * BN_RSQ) + bnb[cc];
        zp[k] = f2bf(lrelu(x, 0.01f));
    }
    *reinterpret_cast<ushort4*>(&z[(size_t)n * 168 + g * 4]) = zo;
}

// ---------- GATv2 linear projections ----------
template <int IND, int HC>
__global__ void gat_lin(const float* __restrict__ X,
                        const float* __restrict__ Wl, const float* __restrict__ bl,
                        const float* __restrict__ Wr, const float* __restrict__ br,
                        float* __restrict__ xl, float* __restrict__ xr, int N)
{
    int t = blockIdx.x * blockDim.x + threadIdx.x;
    if (t >= N * HC) return;
    int n = t / HC, j = t % HC;
    float al = bl[j], ar = br[j];
    const float* xrow = X + (size_t)n * IND;
#pragma unroll 4
    for (int k = 0; k < IND; ++k) {
        float xv = xrow[k];
        al += xv * Wl[k * HC + j];
        ar += xv * Wr[k * HC + j];
    }
    xl[t] = al;
    xr[t] = ar;
}

// ---------- fused GATv2 per (node, head): ONE pass, online softmax ----------
template <int H, int C, int MODE>
__global__ void gat_node(const int* __restrict__ eidx2, const int* __restrict__ off2,
                         const int* __restrict__ e2s, const float* __restrict__ eaext,
                         const float* __restrict__ xl, const float* __restrict__ xr,
                         const float* __restrict__ We, const float* __restrict__ att,
                         const float* __restrict__ b,
                         const float* __restrict__ bng, const float* __restrict__ bnb,
                         void* __restrict__ outv, int E, int N)
{
    int t = blockIdx.x * blockDim.x + threadIdx.x;
    if (t >= N * H) return;
    int n = t / H, h = t % H;

    float xrc[C], atth[C], weh[C];
#pragma unroll
    for (int c = 0; c < C; ++c) {
        xrc[c]  = xr[(size_t)n * (H * C) + h * C + c];
        atth[c] = att[h * C + c];
        weh[c]  = We[h * C + c];
    }

    const int beg = off2[n], end = off2[n + 1];

    float mx = -FLT_MAX, den = 0.0f;
    float accv[C] = {};
    for (int j = beg; j < end; ++j) {
        int e = eidx2[j];
        int s = (e < E) ? e2s[e] : (e - E);
        float ea = eaext[e];
        const float* xls = xl + (size_t)s * (H * C) + h * C;
        float xv[C];
        float lg = 0.0f;
#pragma unroll
        for (int c = 0; c < C; ++c) {
            xv[c] = xls[c];
            float m = xv[c] + xrc[c] + ea * weh[c];
            lg += lrelu(m, 0.2f) * atth[c];
        }
        if (lg > mx) {
            float sc = __expf(mx - lg);
            den *= sc;
#pragma unroll
            for (int c = 0; c < C; ++c) accv[c] *= sc;
            mx = lg;
        }
        float ex = __expf(lg - mx);
        den += ex;
#pragma unroll
        for (int c = 0; c < C; ++c) accv[c] += ex * xv[c];
    }
    float inv = 1.0f / (den + 1e-16f);

#pragma unroll
    for (int c = 0; c < C; ++c) {
        int jch = h * C + c;
        float v = accv[c] * inv + b[jch];
        if (MODE == 1) {
            ((float*)outv)[(size_t)n * (H * C) + jch] = lrelu(v, 0.01f);
        } else {
            v = v * (bng[jch] * BN_RSQ) + bnb[jch];
            ((unsigned short*)outv)[(size_t)n * 168 + 128 + jch] = f2bf(lrelu(v, 0.01f));
        }
    }
}

// ---------- launch ----------
extern "C" void kernel_launch(void* const* d_in, const int* in_sizes, int n_in,
                              void* d_out, int out_size, void* d_ws, size_t ws_size,
                              hipStream_t stream)
{
    const float* features = (const float*)d_in[0];
    const int*   e1       = (const int*)d_in[1];
    const int*   e2       = (const int*)d_in[2];
    const float* ef       = (const float*)d_in[3];
    const float* addf     = (const float*)d_in[4];
    const float* sage_Wl  = (const float*)d_in[5];
    const float* sage_bl  = (const float*)d_in[6];
    const float* sage_Wr  = (const float*)d_in[7];
    const float* g1_Wl = (const float*)d_in[8];
    const float* g1_bl = (const float*)d_in[9];
    const float* g1_Wr = (const float*)d_in[10];
    const float* g1_br = (const float*)d_in[11];
    const float* g1_We = (const float*)d_in[12];
    const float* g1_att = (const float*)d_in[13];
    const float* g1_b = (const float*)d_in[14];
    const float* g2_Wl = (const float*)d_in[15];
    const float* g2_bl = (const float*)d_in[16];
    const float* g2_Wr = (const float*)d_in[17];
    const float* g2_br = (const float*)d_in[18];
    const float* g2_We = (const float*)d_in[19];
    const float* g2_att = (const float*)d_in[20];
    const float* g2_b = (const float*)d_in[21];
    const float* fc1_W = (const float*)d_in[22];
    const float* fc1_b = (const float*)d_in[23];
    const float* fc2_W = (const float*)d_in[24];
    const float* fc2_b = (const float*)d_in[25];
    const float* bnx_g = (const float*)d_in[26];
    const float* bnx_b = (const float*)d_in[27];
    const float* bny_g = (const float*)d_in[28];
    const float* bny_b = (const float*)d_in[29];
    const float* bnf_g = (const float*)d_in[30];
    const float* bnf_b = (const float*)d_in[31];

    const int N = in_sizes[0] / 1024;
    const int E = in_sizes[3];
    const int Eext = E + N;
    const int* e1s = e1, *e1d = e1 + E;
    const int* e2s = e2, *e2d = e2 + E;
    const int nb = (N + SCAN_B - 1) / SCAN_B;

    char* wb = (char*)d_ws;
    size_t off = 0;
    auto takeB = [&](size_t bytes) { char* p = wb + off; off = (off + bytes + 255) & ~(size_t)255; return p; };
    unsigned short* P = (unsigned short*)takeB((size_t)N * 256 * 2);
    unsigned short* z = (unsigned short*)takeB((size_t)N * 168 * 2);
    float* eaext = (float*)takeB((size_t)Eext * 4);
    float* xl1   = (float*)takeB((size_t)N * 40 * 4);
    float* xr1   = (float*)takeB((size_t)N * 40 * 4);
    float* y1    = (float*)takeB((size_t)N * 40 * 4);
    float* xl2   = (float*)takeB((size_t)N * 20 * 4);
    float* xr2   = (float*)takeB((size_t)N * 20 * 4);
    unsigned short* Btp  = (unsigned short*)takeB((size_t)256 * 1024 * 2);
    unsigned short* Bt1p = (unsigned short*)takeB((size_t)36864 * 2);
    // zero-init region: cnt1, cnt2, easum contiguous (256B-aligned start & members)
    char* zero_beg = wb + off;
    int* cnt1    = (int*)takeB((size_t)N * 4);
    int* cnt2    = (int*)takeB((size_t)N * 4);
    float* easum = (float*)takeB((size_t)N * 4);
    size_t zero_len = (size_t)((wb + off) - zero_beg);
    int* off1  = (int*)takeB((size_t)(N + 1) * 4);
    int* off2  = (int*)takeB((size_t)(N + 1) * 4);
    int* bsum1 = (int*)takeB(SCAN_B * 4);
    int* bsum2 = (int*)takeB(SCAN_B * 4);
    int* srcs1 = (int*)takeB((size_t)E * 4);
    int* eidx2 = (int*)takeB((size_t)Eext * 4);

    const int B = 256;
    const int n16 = (int)(zero_len / 16);
    zero_ws<<<(n16 + B - 1) / B, B, 0, stream>>>((uint4*)zero_beg, n16);

    conv_wsage<<<(256 * 1024 + B - 1) / B, B, 0, stream>>>(sage_Wl, sage_Wr, Btp);
    conv_wfc1<<<(36864 + B - 1) / B, B, 0, stream>>>(fc1_W, Bt1p);

    edge_count<<<(E + B - 1) / B, B, 0, stream>>>(e1d, e2d, ef, cnt1, cnt2, easum, eaext, E);

    scan1<<<dim3(nb, 2), SCAN_B, 0, stream>>>(cnt1, cnt2, off1, off2, bsum1, bsum2, N);
    scan2<<<dim3(1, 2), SCAN_B, 0, stream>>>(bsum1, bsum2, nb);
    scan3<<<dim3(nb, 2), SCAN_B, 0, stream>>>(off1, off2, bsum1, bsum2, cnt1, cnt2,
                                              easum, eaext, E, N);

    fill_both<<<(E + Eext + B - 1) / B, B, 0, stream>>>(e1s, e1d, e2d, off1, off2,
                                                        cnt1, cnt2, srcs1, eidx2, E, Eext);

    const int mtiles = (N + 63) / 64;
    gemm_sage_mfma<<<mtiles, 256, 0, stream>>>(features, Btp, P, N);
    sage_gather<<<(N * 32 + B - 1) / B, B, 0, stream>>>(srcs1, off1, P, sage_bl, bnx_g, bnx_b, z, N);

    gat_lin<20, 40><<<(N * 40 + B - 1) / B, B, 0, stream>>>(addf, g1_Wl, g1_bl, g1_Wr, g1_br, xl1, xr1, N);
    gat_node<4, 10, 1><<<(N * 4 + B - 1) / B, B, 0, stream>>>(
        eidx2, off2, e2s, eaext, xl1, xr1, g1_We, g1_att, g1_b,
        nullptr, nullptr, (void*)y1, E, N);

    gat_lin<40, 20><<<(N * 20 + B - 1) / B, B, 0, stream>>>(y1, g2_Wl, g2_bl, g2_Wr, g2_br, xl2, xr2, N);
    gat_node<4, 5, 2><<<(N * 4 + B - 1) / B, B, 0, stream>>>(
        eidx2, off2, e2s, eaext, xl2, xr2, g2_We, g2_att, g2_b,
        bny_g, bny_b, (void*)z, E, N);

    mlp_mfma<<<mtiles, 256, 0, stream>>>(z, addf, Bt1p, fc1_b, bnf_g, bnf_b, fc2_W, fc2_b,
                                         (float*)d_out, N);
}